// Round 14
// baseline (1568.727 us; speedup 1.0000x reference)
//
#include <hip/hip_runtime.h>
#include <hip/hip_bf16.h>

// ---------------- problem constants ----------------
#define QN 1024
#define NDB 200000
#define NDB_PAD 200064        // 3126 subtiles of 64 rows
#define PDBW 257
#define CDIM 256
#define TK 16
#define NEGF (-1e30f)
#define MIN_SIM_C 0.05f
#define MIN_VOTES_C 0.3f

// fast path: 256 chunks x 2 mtiles (512 thr, 8 waves x 64 q); fp8 db in ws
#define NCH 256
#define THETA 0.19f           // P(sim>THETA)=1.18e-3; true 16th-best ~0.236 (fp8 err ~3e-3 -> ~15 sigma)
#define CAPQ 10               // per-(query,chunk) cap (lambda~0.92, P(any over)~1e-3 -> flag+fallback)
// fallback (round-1, proven) path
#define NCHUNK1 49
#define CPQ1 (NCHUNK1*32)

typedef __attribute__((ext_vector_type(8))) short bf16x8;
typedef __attribute__((ext_vector_type(4))) float f32x4;
typedef __attribute__((ext_vector_type(8))) int   i32x8;
typedef __attribute__((ext_vector_type(4))) int   i32x4;

__device__ __forceinline__ short f2bf(float f) {
  union { float f; unsigned u; } x; x.f = f;
  unsigned u = x.u;
  return (short)((u + 0x7fffu + ((u >> 16) & 1u)) >> 16);  // RNE
}

__device__ __forceinline__ void async_copy16(const void* gp, void* lp) {
  __builtin_amdgcn_global_load_lds(
      (__attribute__((address_space(1))) void*)gp,
      (__attribute__((address_space(3))) void*)lp, 16, 0, 0);
}

// pack 4 floats -> 4 fp8 e4m3 bytes (same converter feeds A and B, so any
// consistent lane-position->k mapping cancels in the MFMA dot product)
__device__ __forceinline__ unsigned pk_fp8x4(float a, float b, float c, float d) {
  unsigned w = (unsigned)__builtin_amdgcn_cvt_pk_fp8_f32(a, b, 0, false);
  w = (unsigned)__builtin_amdgcn_cvt_pk_fp8_f32(c, d, (int)w, true);
  return w;
}

// chunk geometry: 3126 subtiles over 256 chunks (0..53 have 13, rest 12)
__device__ __forceinline__ int chunk_nsub(int c) { return 12 + (c < 54 ? 1 : 0); }
__device__ __forceinline__ int chunk_row0(int c) { return (12*c + (c < 54 ? c : 54)) << 6; }

// ---------------------------------------------------------------------------
// Kernel 0: pdb fp32 -> fp8 e4m3, PRE-SWIZZLED global layout (8B piece
// p -> p ^ ((r&15)<<1), matching the filter's XOR'd ds_read), zero-pad rows.
// Linear global_load_lds staging then preserves the swizzle (both-sides rule).
// Also zeroes the fallback flag. (Proven R6-R8.)
// ---------------------------------------------------------------------------
__global__ __launch_bounds__(256) void convert_db_kernel(
    const float* __restrict__ pdb, unsigned char* __restrict__ dbb,
    int* __restrict__ flag)
{
  if (blockIdx.x == 0 && threadIdx.x == 0) *flag = 0;
  const int wv = (int)threadIdx.x >> 6, lane = (int)threadIdx.x & 63;
  for (int r = (int)blockIdx.x*4 + wv; r < NDB_PAD; r += (int)gridDim.x*4) {
    unsigned pack = 0u;
    if (r < NDB) {
      const float* p = pdb + (size_t)r*PDBW + lane*4;
      pack = pk_fp8x4(p[0], p[1], p[2], p[3]);
    }
    const int piece = lane >> 1;                       // 8B piece index 0..31
    const int ps    = piece ^ ((r & 15) << 1);         // == 16B-pair ^ (r&15)
    *(unsigned*)(dbb + (size_t)r*256 + ps*8 + (lane & 1)*4) = pack;
  }
}

// ---------------------------------------------------------------------------
// Kernel 1: MX-fp8 (K=128, unit scale) MFMA sims + register theta-filter +
// wave-private LDS survivor lists (packed 4B entries: bf16val<<16 | local idx).
// grid (256 chunks, 2 mtiles) = 512 blocks (2/CU, 16 waves/CU), 512 thr
// (8 waves x 64 q). Staging via global_load_lds (32B/thread, NO staging regs,
// NO cvt VALU -- the R10/R13 plateau was redundant fp32 re-reads + staging).
// fn-SPLIT accumulator: MFMA+filter twice per tile with acc[4][2]=32 regs ->
// live set ~116 (aq 64 + acc 32 + addr) under the 128-reg cap: no spill.
// One barrier per 64-row subtile (R7-proven rotation). LDS 54KB.
// ---------------------------------------------------------------------------
__global__ __launch_bounds__(512, 4) void sims_filter_kernel(
    const float* __restrict__ qd, const unsigned char* __restrict__ dbb,
    unsigned int* __restrict__ seg_g, unsigned int* __restrict__ cnt_g)
{
  __shared__ __align__(16) char db_lds[2][64 * 256];   // 32768 B (fp8, swizzled)
  __shared__ unsigned seg_lds[8][64][CAPQ];            // 20480 B (wave-private)
  __shared__ int lcnt[8][64];                          // 2048 B (wave-private)

  const int tid  = (int)threadIdx.x;
  const int lane = tid & 63;
  const int wv   = tid >> 6;          // 0..7
  const int cid  = (int)blockIdx.x;   // 0..255
  const int mt   = (int)blockIdx.y;   // 0..1
  const int nsub = chunk_nsub(cid);
  const int row0 = chunk_row0(cid);

  lcnt[wv][lane] = 0;   // wave-private, no barrier needed

  const int l15  = lane & 15;
  const int egrp = lane >> 4;         // k-chunk group 0..3 (32 k each)
  const int rowb = egrp << 2;
  const int colb = l15;

  // ---- Q fragments: fp32 -> fp8 packed i32x8; wave wv owns 64 queries ----
  i32x8 aq[4][2];
  {
    #pragma unroll
    for (int fm = 0; fm < 4; ++fm) {
      const float* qrow = qd + (size_t)(mt*512 + wv*64 + fm*16 + l15)*CDIM;
      #pragma unroll
      for (int kk = 0; kk < 2; ++kk) {
        const float* p = qrow + kk*128 + egrp*32;
        i32x8 a;
        #pragma unroll
        for (int d = 0; d < 8; ++d) {
          float4 x = *(const float4*)(p + d*4);
          a[d] = (int)pk_fp8x4(x.x, x.y, x.z, x.w);
        }
        aq[fm][kk] = a;
      }
    }
  }

  const char* dbbase = (const char*)dbb;
#define STAGE(bufi, tile) do { \
    const char* _src = dbbase + ((size_t)(row0 + (tile)*64) * 256) + tid*32; \
    char* _dst = (char*)db_lds[(bufi)] + tid*32; \
    async_copy16(_src,      _dst); \
    async_copy16(_src + 16, _dst + 16); \
  } while (0)

  STAGE(0, 0);   // prologue: tile 0 loads in flight

  for (int s = 0; s < nsub; ++s) {
    // tile s's loads were issued a full iteration ago -> this drain is cheap
    asm volatile("s_waitcnt vmcnt(0)" ::: "memory");
    __builtin_amdgcn_sched_barrier(0);
    __builtin_amdgcn_s_barrier();       // tile s visible; tile s-1 reads drained
    __builtin_amdgcn_sched_barrier(0);

    // issue next tile into the other buffer NOW (overwrites tile s-1 -- safe;
    // DMA latency hides under the MFMA+filter phases below)
    if (s + 1 < nsub) STAGE((s + 1) & 1, s + 1);

    const char* dbt = (const char*)db_lds[s & 1];
    // ---- fn-split: two halves, each MFMA (acc[4][2]) then filter ----
    #pragma unroll
    for (int h = 0; h < 2; ++h) {
      f32x4 acc[4][2];
      #pragma unroll
      for (int fm = 0; fm < 4; ++fm)
        #pragma unroll
        for (int fnl = 0; fnl < 2; ++fnl)
          acc[fm][fnl] = (f32x4){0.f, 0.f, 0.f, 0.f};

      __builtin_amdgcn_s_setprio(1);
      #pragma unroll
      for (int kk = 0; kk < 2; ++kk) {
        #pragma unroll
        for (int fnl = 0; fnl < 2; ++fnl) {
          const int fn = h*2 + fnl;
          const char* rowp = dbt + (fn*16 + l15)*256;
          const int mbase = kk*8 + egrp*2;
          i32x4 lo = *(const i32x4*)(rowp + (((mbase    ) ^ l15) << 4));
          i32x4 hi = *(const i32x4*)(rowp + (((mbase + 1) ^ l15) << 4));
          i32x8 b = __builtin_shufflevector(lo, hi, 0, 1, 2, 3, 4, 5, 6, 7);
          #pragma unroll
          for (int fm = 0; fm < 4; ++fm)
            acc[fm][fnl] = __builtin_amdgcn_mfma_scale_f32_16x16x128_f8f6f4(
                aq[fm][kk], b, acc[fm][fnl],
                0 /*fmtA=fp8*/, 0 /*fmtB=fp8*/,
                0, 0x7F7F7F7Fu /*scaleA=1.0*/, 0, 0x7F7F7F7Fu /*scaleB=1.0*/);
        }
      }
      __builtin_amdgcn_s_setprio(0);

      // theta-filter; packed 4B append (value bf16 hi | chunk-local idx lo)
      #pragma unroll
      for (int fm = 0; fm < 4; ++fm)
        #pragma unroll
        for (int fnl = 0; fnl < 2; ++fnl) {
          const f32x4 a = acc[fm][fnl];
          const float m = fmaxf(fmaxf(a[0], a[1]), fmaxf(a[2], a[3]));
          if (m > THETA) {
            #pragma unroll
            for (int j = 0; j < 4; ++j) {
              if (a[j] > THETA) {
                const int ql = fm*16 + rowb + j;
                const int slot = atomicAdd(&lcnt[wv][ql], 1);
                if (slot < CAPQ) {
                  const unsigned v16 = (unsigned)(unsigned short)f2bf(a[j]);
                  const unsigned loc = (unsigned)(s*64 + (h*2 + fnl)*16 + colb);
                  seg_lds[wv][ql][slot] = (v16 << 16) | loc;
                }
              }
            }
          }
        }
    }

    // drain own ds ops before the next barrier: buffer rotation hazard-free
    asm volatile("s_waitcnt lgkmcnt(0)" ::: "memory");
    __builtin_amdgcn_sched_barrier(0);
  }
#undef STAGE

  // ---- flush wave-private survivor lists to global (lane == wave-local q) ----
  {
    const int cnt = lcnt[wv][lane];
    const int qg = mt*512 + wv*64 + lane;
    cnt_g[qg*NCH + cid] = (unsigned)cnt;
    const int nc = min(cnt, CAPQ);
    unsigned* dst = seg_g + (size_t)(qg*NCH + cid)*CAPQ;
    for (int j = 0; j < nc; ++j) dst[j] = seg_lds[wv][lane][j];
  }
}

// ---------------------------------------------------------------------------
// Kernel 2: per-query gather of survivors -> exact top-16 -> vote.
// Unpacks 4B entries (value = bf16 hi bits; idx = chunk row0 + local).
// Self-check: overflow or <16 survivors -> set flag (triggers fallback).
// ---------------------------------------------------------------------------
__global__ __launch_bounds__(64) void gather_vote_kernel(
    const float* __restrict__ pdb,
    const unsigned* __restrict__ seg_g, const unsigned* __restrict__ cnt_g,
    int* __restrict__ out_label, float* __restrict__ out_s, int* __restrict__ flag)
{
  __shared__ float    cv[NCH*CAPQ];   // 2560
  __shared__ unsigned ci[NCH*CAPQ];
  const int q    = (int)blockIdx.x;
  const int lane = (int)threadIdx.x;

  bool over = false;
  int tot = 0;
  #pragma unroll
  for (int h = 0; h < NCH/64; ++h) {
    const int c = h*64 + lane;
    const int cnt = (int)cnt_g[q*NCH + c];
    over |= (cnt > CAPQ);
    const int nc = min(cnt, CAPQ);
    tot += nc;
    const int r0c = chunk_row0(c);
    const unsigned* src = seg_g + (size_t)(q*NCH + c)*CAPQ;
    for (int j = 0; j < CAPQ; ++j) {
      float v = NEGF; unsigned idx = 0u;
      if (j < nc) {
        const unsigned e = src[j];
        v = __uint_as_float(e & 0xFFFF0000u);   // bf16 value in high bits
        idx = (unsigned)(r0c + (int)(e & 0xFFFFu));
      }
      cv[c*CAPQ + j] = v;
      ci[c*CAPQ + j] = idx;
    }
  }
  #pragma unroll
  for (int off = 32; off >= 1; off >>= 1) tot += __shfl_xor(tot, off);
  __syncthreads();

  float topv[TK]; int topid[TK];
  #pragma unroll
  for (int r = 0; r < TK; ++r) {
    float bv = NEGF; int bp = -1;
    #pragma unroll 4
    for (int j = 0; j < (NCH*CAPQ)/64; ++j) {
      const int p = j*64 + lane;
      const float v = cv[p];
      if (v > bv) { bv = v; bp = p; }
    }
    #pragma unroll
    for (int off = 32; off >= 1; off >>= 1) {
      const float ov = __shfl_xor(bv, off);
      const int   op = __shfl_xor(bp, off);
      if (ov > bv || (ov == bv && ((unsigned)op < (unsigned)bp))) { bv = ov; bp = op; }
    }
    topv[r] = bv;
    int id = -2;
    if (bp >= 0 && bv > NEGF) id = (int)pdb[(size_t)ci[bp]*PDBW + CDIM];
    topid[r] = id;
    if (lane == 0 && bp >= 0) cv[bp] = NEGF;
    __syncthreads();
  }

  if (lane == 0) {
    bool mk[TK];
    int nvalid = 0;
    #pragma unroll
    for (int i = 0; i < TK; ++i) {
      mk[i] = (topv[i] >= MIN_SIM_C) && (topid[i] >= 0);
      nvalid += mk[i] ? 1 : 0;
    }
    int maj = 0, majid = 0x7fffffff;
    for (int i = 0; i < TK; ++i) {
      if (!mk[i]) continue;
      int c = 0;
      for (int j = 0; j < TK; ++j) c += (mk[j] && topid[j] == topid[i]) ? 1 : 0;
      if (c > maj || (c == maj && topid[i] < majid)) { maj = c; majid = topid[i]; }
    }
    const float ratio = (float)maj / fmaxf((float)nvalid, 1.0f);
    const bool valid = (maj > 0) && (ratio >= MIN_VOTES_C);
    const int label = valid ? majid : -1;
    float s = 0.f;
    #pragma unroll
    for (int i = 0; i < TK; ++i)
      if (mk[i] && topid[i] == label) s = fmaxf(s, topv[i]);
    out_label[q] = label;
    out_s[q]     = s;
  }
  const bool bad = (__ballot(over) != 0ull) || (tot < TK);
  if (lane == 0 && bad) atomicOr(flag, 1);
}

// ---------------------------------------------------------------------------
// Fallback stage 1 (round-1, proven): gated on flag
// ---------------------------------------------------------------------------
__global__ __launch_bounds__(256, 2) void sims_topk1_kernel(
    const float* __restrict__ qd, const float* __restrict__ pdb,
    float* __restrict__ cand_val, unsigned int* __restrict__ cand_idx,
    const int* __restrict__ gate)
{
  if (gate && *gate == 0) return;
  __shared__ __align__(16) short db_lds[128 * 264];
  float* sims = (float*)db_lds;

  const int tid  = (int)threadIdx.x;
  const int lane = tid & 63;
  const int wv   = tid >> 6;
  const int cid   = (int)blockIdx.x;
  const int mtile = (int)blockIdx.y;

  bf16x8 aq[2][8];
  {
    const int l15 = lane & 15;
    const int kb  = (lane >> 4) << 3;
    #pragma unroll
    for (int fm = 0; fm < 2; ++fm) {
      const int row = mtile*128 + wv*32 + fm*16 + l15;
      #pragma unroll
      for (int kk = 0; kk < 8; ++kk) {
        const float* p = qd + (size_t)row*CDIM + kk*32 + kb;
        float4 x0 = *(const float4*)p;
        float4 x1 = *(const float4*)(p + 4);
        bf16x8 a;
        a[0]=f2bf(x0.x); a[1]=f2bf(x0.y); a[2]=f2bf(x0.z); a[3]=f2bf(x0.w);
        a[4]=f2bf(x1.x); a[5]=f2bf(x1.y); a[6]=f2bf(x1.z); a[7]=f2bf(x1.w);
        aq[fm][kk] = a;
      }
    }
  }

  float    tv[TK];
  unsigned ti[TK];
  #pragma unroll
  for (int i = 0; i < TK; ++i) { tv[i] = NEGF; ti[i] = 0u; }
  float minv = NEGF; int minp = 0;

  const int g0chunk = cid * 4096;
  const int q_l  = tid & 127;
  const int half = tid >> 7;

  for (int s = 0; s < 32; ++s) {
    const int g0 = g0chunk + s*128;
    {
      const int rb = tid >> 6;
      const int c4 = (tid & 63) << 2;
      for (int i = 0; i < 32; ++i) {
        const int rl = i*4 + rb;
        const int g  = g0 + rl;
        float v0, v1, v2, v3;
        if (g < NDB) {
          const float* p = pdb + (size_t)g*PDBW + c4;
          v0 = p[0]; v1 = p[1]; v2 = p[2]; v3 = p[3];
        } else { v0 = v1 = v2 = v3 = 0.f; }
        short* d = &db_lds[rl*264 + c4];
        d[0]=f2bf(v0); d[1]=f2bf(v1); d[2]=f2bf(v2); d[3]=f2bf(v3);
      }
    }
    __syncthreads();

    f32x4 acc[2][8];
    #pragma unroll
    for (int fm = 0; fm < 2; ++fm)
      #pragma unroll
      for (int fn = 0; fn < 8; ++fn)
        acc[fm][fn] = (f32x4){0.f, 0.f, 0.f, 0.f};
    {
      const int l15 = lane & 15;
      const int kb  = (lane >> 4) << 3;
      #pragma unroll
      for (int kk = 0; kk < 8; ++kk) {
        bf16x8 b[8];
        #pragma unroll
        for (int fn = 0; fn < 8; ++fn)
          b[fn] = *(const bf16x8*)&db_lds[(fn*16 + l15)*264 + kk*32 + kb];
        #pragma unroll
        for (int fn = 0; fn < 8; ++fn) {
          acc[0][fn] = __builtin_amdgcn_mfma_f32_16x16x32_bf16(aq[0][kk], b[fn], acc[0][fn], 0, 0, 0);
          acc[1][fn] = __builtin_amdgcn_mfma_f32_16x16x32_bf16(aq[1][kk], b[fn], acc[1][fn], 0, 0, 0);
        }
      }
    }
    __syncthreads();

    {
      const int colb = lane & 15;
      const int rowb = (lane >> 4) << 2;
      #pragma unroll
      for (int fm = 0; fm < 2; ++fm)
        #pragma unroll
        for (int fn = 0; fn < 8; ++fn)
          #pragma unroll
          for (int j = 0; j < 4; ++j)
            sims[(wv*32 + fm*16 + rowb + j)*129 + fn*16 + colb] = acc[fm][fn][j];
    }
    __syncthreads();

    {
      const int cb = half * 64;
      #pragma unroll 4
      for (int c = 0; c < 64; ++c) {
        const int colc = cb + c;
        const float v = sims[q_l*129 + colc];
        const int g = g0 + colc;
        if (v > minv && g < NDB) {
          #pragma unroll
          for (int i = 0; i < TK; ++i) if (i == minp) { tv[i] = v; ti[i] = (unsigned)g; }
          minv = tv[0]; minp = 0;
          #pragma unroll
          for (int i = 1; i < TK; ++i) if (tv[i] < minv) { minv = tv[i]; minp = i; }
        }
      }
    }
    __syncthreads();
  }

  {
    const int qg = mtile*128 + q_l;
    float*    pv = cand_val + ((size_t)qg*NCHUNK1 + cid)*32 + half*TK;
    unsigned* pi = cand_idx + ((size_t)qg*NCHUNK1 + cid)*32 + half*TK;
    #pragma unroll
    for (int i = 0; i < TK; ++i) { pv[i] = tv[i]; pi[i] = ti[i]; }
  }
}

// ---------------------------------------------------------------------------
// Fallback stage 2 (round-1, proven): gated on flag
// ---------------------------------------------------------------------------
template<int CPQ>
__global__ __launch_bounds__(64) void merge_vote_kernel(
    const float* __restrict__ pdb,
    const float* __restrict__ cand_val, const unsigned* __restrict__ cand_idx,
    int* __restrict__ out_label, float* __restrict__ out_s,
    const int* __restrict__ gate)
{
  if (gate && *gate == 0) return;
  __shared__ float    cv[CPQ];
  __shared__ unsigned ci[CPQ];
  const int q    = (int)blockIdx.x;
  const int lane = (int)threadIdx.x;

  for (int j = lane; j < CPQ; j += 64) {
    cv[j] = cand_val[(size_t)q*CPQ + j];
    ci[j] = cand_idx[(size_t)q*CPQ + j];
  }
  __syncthreads();

  float topv[TK]; int topid[TK];
  #pragma unroll
  for (int r = 0; r < TK; ++r) {
    float bv = NEGF; int bp = -1;
    for (int j = lane; j < CPQ; j += 64) {
      const float v = cv[j];
      if (v > bv) { bv = v; bp = j; }
    }
    #pragma unroll
    for (int off = 32; off >= 1; off >>= 1) {
      const float ov = __shfl_xor(bv, off);
      const int   op = __shfl_xor(bp, off);
      if (ov > bv || (ov == bv && ((unsigned)op < (unsigned)bp))) { bv = ov; bp = op; }
    }
    topv[r] = bv;
    int id = -2;
    if (bp >= 0 && bv > NEGF) id = (int)pdb[(size_t)ci[bp]*PDBW + CDIM];
    topid[r] = id;
    if (lane == 0 && bp >= 0) cv[bp] = NEGF;
    __syncthreads();
  }

  if (lane == 0) {
    bool mk[TK];
    int nvalid = 0;
    #pragma unroll
    for (int i = 0; i < TK; ++i) {
      mk[i] = (topv[i] >= MIN_SIM_C) && (topid[i] >= 0);
      nvalid += mk[i] ? 1 : 0;
    }
    int maj = 0, majid = 0x7fffffff;
    for (int i = 0; i < TK; ++i) {
      if (!mk[i]) continue;
      int c = 0;
      for (int j = 0; j < TK; ++j) c += (mk[j] && topid[j] == topid[i]) ? 1 : 0;
      if (c > maj || (c == maj && topid[i] < majid)) { maj = c; majid = topid[i]; }
    }
    const float ratio = (float)maj / fmaxf((float)nvalid, 1.0f);
    const bool valid = (maj > 0) && (ratio >= MIN_VOTES_C);
    const int label = valid ? majid : -1;
    float s = 0.f;
    #pragma unroll
    for (int i = 0; i < TK; ++i)
      if (mk[i] && topid[i] == label) s = fmaxf(s, topv[i]);
    out_label[q] = label;
    out_s[q]     = s;
  }
}

// ---------------------------------------------------------------------------
// Stage 3: overlap removal + final outputs
// ---------------------------------------------------------------------------
__device__ __forceinline__ bool finitef(float v) {
  return ((__float_as_uint(v) >> 23) & 0xffu) != 0xffu;
}

__global__ __launch_bounds__(64) void finalize_kernel(
    const float* __restrict__ boxes, const int* __restrict__ labels,
    const float* __restrict__ svals, float* __restrict__ out)
{
  const int x    = (int)blockIdx.x;
  const int lane = (int)threadIdx.x;
  const int lx = labels[x];
  const float bx1 = boxes[x*4+0], by1 = boxes[x*4+1];
  const float bx2 = boxes[x*4+2], by2 = boxes[x*4+3];
  const float ax = (bx2 - bx1) * (by2 - by1);

  bool flag = false;
  if (lx >= 0) {
    for (int y = lane; y < QN; y += 64) {
      if (y == x) continue;
      if (labels[y] != lx) continue;
      const float c1 = boxes[y*4+0], c2 = boxes[y*4+1];
      const float c3 = boxes[y*4+2], c4 = boxes[y*4+3];
      const float ay = (c3 - c1) * (c4 - c2);
      const float xi1 = fmaxf(bx1, c1), yi1 = fmaxf(by1, c2);
      const float xi2 = fminf(bx2, c3), yi2 = fminf(by2, c4);
      const float inter = fmaxf(xi2 - xi1, 0.f) * fmaxf(yi2 - yi1, 0.f);
      const float asmall = fminf(ax, ay);
      const float ov = (asmall > 0.f) ? inter / fmaxf(asmall, 1e-12f) : 0.f;
      if (ov >= 0.5f && ay <= ax) flag = true;
    }
  }
  const bool removed = (__ballot(flag) != 0ull);
  const int label = removed ? -1 : lx;
  const float s = svals[x];
  const bool fin = finitef(s) && finitef(bx1) && finitef(by1) && finitef(bx2) && finitef(by2);
  const bool valid = (label >= 0) && fin;

  if (lane == 0) {
    out[4096 + x] = valid ? s : 0.f;
    out[5120 + x] = (float)(valid ? label : -1);
  }
  if (lane < 4) out[x*4 + lane] = boxes[x*4 + lane];
}

// ---------------------------------------------------------------------------
extern "C" void kernel_launch(void* const* d_in, const int* in_sizes, int n_in,
                              void* d_out, int out_size, void* d_ws, size_t ws_size,
                              hipStream_t stream)
{
  const float* boxes = (const float*)d_in[0];
  const float* qd    = (const float*)d_in[1];
  const float* pdb   = (const float*)d_in[2];
  float* out = (float*)d_out;
  char* ws = (char*)d_ws;

  const size_t db_bytes  = (size_t)NDB_PAD * 256;             //  51,216,384 (fp8)
  const size_t seg_bytes = (size_t)QN * NCH * CAPQ * 4;       //  10,485,760
  const size_t cnt_bytes = (size_t)QN * NCH * 4;              //   1,048,576
  const size_t c1_bytes  = (size_t)QN * CPQ1 * 8;             //  12,845,056 (fallback, aliases seg+cnt)
  const size_t A_bytes   = (seg_bytes + cnt_bytes > c1_bytes) ? seg_bytes + cnt_bytes : c1_bytes;
  const size_t need = db_bytes + A_bytes + (size_t)QN*8 + 64;

  if (ws_size >= need) {
    unsigned char* dbb = (unsigned char*)ws;
    char* A = ws + db_bytes;
    unsigned* seg_g = (unsigned*)A;
    unsigned* cnt_g = (unsigned*)(A + seg_bytes);
    float*    cand_val = (float*)A;
    unsigned* cand_idx = (unsigned*)(A + (size_t)QN*CPQ1*4);
    int*      labels   = (int*)(ws + db_bytes + A_bytes);
    float*    svals    = (float*)(ws + db_bytes + A_bytes + (size_t)QN*4);
    int*      flag     = (int*)(ws + db_bytes + A_bytes + (size_t)QN*8);

    hipLaunchKernelGGL(convert_db_kernel, dim3(2048), dim3(256), 0, stream, pdb, dbb, flag);
    hipLaunchKernelGGL(sims_filter_kernel, dim3(NCH, 2), dim3(512), 0, stream,
                       qd, dbb, seg_g, cnt_g);
    hipLaunchKernelGGL(gather_vote_kernel, dim3(QN), dim3(64), 0, stream,
                       pdb, seg_g, cnt_g, labels, svals, flag);
    hipLaunchKernelGGL(sims_topk1_kernel, dim3(NCHUNK1, 8), dim3(256), 0, stream,
                       qd, pdb, cand_val, cand_idx, flag);
    hipLaunchKernelGGL((merge_vote_kernel<CPQ1>), dim3(QN), dim3(64), 0, stream,
                       pdb, cand_val, cand_idx, labels, svals, flag);
    hipLaunchKernelGGL(finalize_kernel, dim3(QN), dim3(64), 0, stream,
                       boxes, labels, svals, out);
  } else {
    const size_t n1 = (size_t)QN * CPQ1;
    float*    cand_val = (float*)ws;
    unsigned* cand_idx = (unsigned*)(ws + n1*4);
    int*      labels   = (int*)(ws + n1*8);
    float*    svals    = (float*)(ws + n1*8 + (size_t)QN*4);

    hipLaunchKernelGGL(sims_topk1_kernel, dim3(NCHUNK1, 8), dim3(256), 0, stream,
                       qd, pdb, cand_val, cand_idx, (const int*)nullptr);
    hipLaunchKernelGGL((merge_vote_kernel<CPQ1>), dim3(QN), dim3(64), 0, stream,
                       pdb, cand_val, cand_idx, labels, svals, (const int*)nullptr);
    hipLaunchKernelGGL(finalize_kernel, dim3(QN), dim3(64), 0, stream,
                       boxes, labels, svals, out);
  }
}

// Round 15
// 201.606 us; speedup vs baseline: 7.7811x; 7.7811x over previous
//
#include <hip/hip_runtime.h>
#include <hip/hip_bf16.h>

// ---------------- problem constants ----------------
#define QN 1024
#define NDB 200000
#define NDB_PAD 200064        // 3126 subtiles of 64 rows
#define PDBW 257
#define CDIM 256
#define TK 16
#define NEGF (-1e30f)
#define MIN_SIM_C 0.05f
#define MIN_VOTES_C 0.3f

// fast path: 256 chunks x 2 mtiles (512 thr, 8 waves x 64 q); fp8 db in ws
#define NCH 256
#define THETA 0.19f           // P(sim>THETA)=1.18e-3; true 16th-best ~0.236 (fp8 err ~3e-3 -> ~15 sigma)
#define CAPQ 10               // per-(query,chunk) cap (lambda~0.92, P(any over)~3e-5 -> flag+fallback)
// fallback (round-1, proven) path
#define NCHUNK1 49
#define CPQ1 (NCHUNK1*32)

typedef __attribute__((ext_vector_type(8))) short bf16x8;
typedef __attribute__((ext_vector_type(4))) float f32x4;
typedef __attribute__((ext_vector_type(8))) int   i32x8;
typedef __attribute__((ext_vector_type(4))) int   i32x4;

__device__ __forceinline__ short f2bf(float f) {
  union { float f; unsigned u; } x; x.f = f;
  unsigned u = x.u;
  return (short)((u + 0x7fffu + ((u >> 16) & 1u)) >> 16);  // RNE
}

__device__ __forceinline__ void async_copy16(const void* gp, void* lp) {
  __builtin_amdgcn_global_load_lds(
      (__attribute__((address_space(1))) void*)gp,
      (__attribute__((address_space(3))) void*)lp, 16, 0, 0);
}

// pack 4 floats -> 4 fp8 e4m3 bytes (same converter feeds A and B, so any
// consistent lane-position->k mapping cancels in the MFMA dot product)
__device__ __forceinline__ unsigned pk_fp8x4(float a, float b, float c, float d) {
  unsigned w = (unsigned)__builtin_amdgcn_cvt_pk_fp8_f32(a, b, 0, false);
  w = (unsigned)__builtin_amdgcn_cvt_pk_fp8_f32(c, d, (int)w, true);
  return w;
}

// chunk geometry: 3126 subtiles over 256 chunks (0..53 have 13, rest 12)
__device__ __forceinline__ int chunk_nsub(int c) { return 12 + (c < 54 ? 1 : 0); }
__device__ __forceinline__ int chunk_row0(int c) { return (12*c + (c < 54 ? c : 54)) << 6; }

// ---------------------------------------------------------------------------
// Kernel 0: pdb fp32 -> fp8 e4m3, PRE-SWIZZLED global layout (8B piece
// p -> p ^ ((r&15)<<1), matching the filter's XOR'd ds_read), zero-pad rows.
// Linear global_load_lds staging then preserves the swizzle (both-sides rule).
// Also zeroes the fallback flag. (Proven R6-R8.)
// ---------------------------------------------------------------------------
__global__ __launch_bounds__(256) void convert_db_kernel(
    const float* __restrict__ pdb, unsigned char* __restrict__ dbb,
    int* __restrict__ flag)
{
  if (blockIdx.x == 0 && threadIdx.x == 0) *flag = 0;
  const int wv = (int)threadIdx.x >> 6, lane = (int)threadIdx.x & 63;
  for (int r = (int)blockIdx.x*4 + wv; r < NDB_PAD; r += (int)gridDim.x*4) {
    unsigned pack = 0u;
    if (r < NDB) {
      const float* p = pdb + (size_t)r*PDBW + lane*4;
      pack = pk_fp8x4(p[0], p[1], p[2], p[3]);
    }
    const int piece = lane >> 1;                       // 8B piece index 0..31
    const int ps    = piece ^ ((r & 15) << 1);         // == 16B-pair ^ (r&15)
    *(unsigned*)(dbb + (size_t)r*256 + ps*8 + (lane & 1)*4) = pack;
  }
}

// ---------------------------------------------------------------------------
// Kernel 1: MX-fp8 (K=128, unit scale) MFMA sims + register theta-filter +
// wave-private LDS survivor lists (packed 4B entries: bf16val<<16 | local idx).
// grid (256 chunks, 2 mtiles) = 512 blocks (2/CU, 16 waves/CU), 512 thr
// (8 waves x 64 q). Staging via global_load_lds with the HW-mandated
// wave-uniform-base + lane*16 pattern (R14 BUG: tid*32 stride broke this --
// DMA deposits at base+lane*16 regardless, tile was garbage, flag fired,
// fallback ran at 1324us). Wave wv copies its 2KB slice as 2x 1024B batches.
// fn-SPLIT accumulator: MFMA+filter twice per tile with acc[4][2]=32 regs ->
// live set ~116 (aq 64 + acc 32 + addr) under the 128-reg cap: no spill.
// One barrier per 64-row subtile (R7-proven rotation). LDS 54KB.
// ---------------------------------------------------------------------------
__global__ __launch_bounds__(512, 4) void sims_filter_kernel(
    const float* __restrict__ qd, const unsigned char* __restrict__ dbb,
    unsigned int* __restrict__ seg_g, unsigned int* __restrict__ cnt_g)
{
  __shared__ __align__(16) char db_lds[2][64 * 256];   // 32768 B (fp8, swizzled)
  __shared__ unsigned seg_lds[8][64][CAPQ];            // 20480 B (wave-private)
  __shared__ int lcnt[8][64];                          // 2048 B (wave-private)

  const int tid  = (int)threadIdx.x;
  const int lane = tid & 63;
  const int wv   = tid >> 6;          // 0..7
  const int cid  = (int)blockIdx.x;   // 0..255
  const int mt   = (int)blockIdx.y;   // 0..1
  const int nsub = chunk_nsub(cid);
  const int row0 = chunk_row0(cid);

  lcnt[wv][lane] = 0;   // wave-private, no barrier needed

  const int l15  = lane & 15;
  const int egrp = lane >> 4;         // k-chunk group 0..3 (32 k each)
  const int rowb = egrp << 2;
  const int colb = l15;

  // ---- Q fragments: fp32 -> fp8 packed i32x8; wave wv owns 64 queries ----
  i32x8 aq[4][2];
  {
    #pragma unroll
    for (int fm = 0; fm < 4; ++fm) {
      const float* qrow = qd + (size_t)(mt*512 + wv*64 + fm*16 + l15)*CDIM;
      #pragma unroll
      for (int kk = 0; kk < 2; ++kk) {
        const float* p = qrow + kk*128 + egrp*32;
        i32x8 a;
        #pragma unroll
        for (int d = 0; d < 8; ++d) {
          float4 x = *(const float4*)(p + d*4);
          a[d] = (int)pk_fp8x4(x.x, x.y, x.z, x.w);
        }
        aq[fm][kk] = a;
      }
    }
  }

  const char* dbbase = (const char*)dbb;
  // HW rule: per-lane lds addr must be wave-uniform-base + lane*16.
  // Wave wv owns bytes [wv*2048, wv*2048+2048) of the 16KB tile: 2 batches.
#define STAGE(bufi, tile) do { \
    const char* _src = dbbase + ((size_t)(row0 + (tile)*64) * 256) + wv*2048 + lane*16; \
    char* _dst = (char*)db_lds[(bufi)] + wv*2048 + lane*16; \
    async_copy16(_src,        _dst); \
    async_copy16(_src + 1024, _dst + 1024); \
  } while (0)

  STAGE(0, 0);   // prologue: tile 0 loads in flight

  for (int s = 0; s < nsub; ++s) {
    // tile s's loads were issued a full iteration ago -> this drain is cheap
    asm volatile("s_waitcnt vmcnt(0)" ::: "memory");
    __builtin_amdgcn_sched_barrier(0);
    __builtin_amdgcn_s_barrier();       // tile s visible; tile s-1 reads drained
    __builtin_amdgcn_sched_barrier(0);

    // issue next tile into the other buffer NOW (overwrites tile s-1 -- safe;
    // DMA latency hides under the MFMA+filter phases below)
    if (s + 1 < nsub) STAGE((s + 1) & 1, s + 1);

    const char* dbt = (const char*)db_lds[s & 1];
    // ---- fn-split: two halves, each MFMA (acc[4][2]) then filter ----
    #pragma unroll
    for (int h = 0; h < 2; ++h) {
      f32x4 acc[4][2];
      #pragma unroll
      for (int fm = 0; fm < 4; ++fm)
        #pragma unroll
        for (int fnl = 0; fnl < 2; ++fnl)
          acc[fm][fnl] = (f32x4){0.f, 0.f, 0.f, 0.f};

      __builtin_amdgcn_s_setprio(1);
      #pragma unroll
      for (int kk = 0; kk < 2; ++kk) {
        #pragma unroll
        for (int fnl = 0; fnl < 2; ++fnl) {
          const int fn = h*2 + fnl;
          const char* rowp = dbt + (fn*16 + l15)*256;
          const int mbase = kk*8 + egrp*2;
          i32x4 lo = *(const i32x4*)(rowp + (((mbase    ) ^ l15) << 4));
          i32x4 hi = *(const i32x4*)(rowp + (((mbase + 1) ^ l15) << 4));
          i32x8 b = __builtin_shufflevector(lo, hi, 0, 1, 2, 3, 4, 5, 6, 7);
          #pragma unroll
          for (int fm = 0; fm < 4; ++fm)
            acc[fm][fnl] = __builtin_amdgcn_mfma_scale_f32_16x16x128_f8f6f4(
                aq[fm][kk], b, acc[fm][fnl],
                0 /*fmtA=fp8*/, 0 /*fmtB=fp8*/,
                0, 0x7F7F7F7Fu /*scaleA=1.0*/, 0, 0x7F7F7F7Fu /*scaleB=1.0*/);
        }
      }
      __builtin_amdgcn_s_setprio(0);

      // theta-filter; packed 4B append (value bf16 hi | chunk-local idx lo)
      #pragma unroll
      for (int fm = 0; fm < 4; ++fm)
        #pragma unroll
        for (int fnl = 0; fnl < 2; ++fnl) {
          const f32x4 a = acc[fm][fnl];
          const float m = fmaxf(fmaxf(a[0], a[1]), fmaxf(a[2], a[3]));
          if (m > THETA) {
            #pragma unroll
            for (int j = 0; j < 4; ++j) {
              if (a[j] > THETA) {
                const int ql = fm*16 + rowb + j;
                const int slot = atomicAdd(&lcnt[wv][ql], 1);
                if (slot < CAPQ) {
                  const unsigned v16 = (unsigned)(unsigned short)f2bf(a[j]);
                  const unsigned loc = (unsigned)(s*64 + (h*2 + fnl)*16 + colb);
                  seg_lds[wv][ql][slot] = (v16 << 16) | loc;
                }
              }
            }
          }
        }
    }

    // drain own ds ops before the next barrier: buffer rotation hazard-free
    asm volatile("s_waitcnt lgkmcnt(0)" ::: "memory");
    __builtin_amdgcn_sched_barrier(0);
  }
#undef STAGE

  // ---- flush wave-private survivor lists to global (lane == wave-local q) ----
  {
    const int cnt = lcnt[wv][lane];
    const int qg = mt*512 + wv*64 + lane;
    cnt_g[qg*NCH + cid] = (unsigned)cnt;
    const int nc = min(cnt, CAPQ);
    unsigned* dst = seg_g + (size_t)(qg*NCH + cid)*CAPQ;
    for (int j = 0; j < nc; ++j) dst[j] = seg_lds[wv][lane][j];
  }
}

// ---------------------------------------------------------------------------
// Kernel 2: per-query gather of survivors -> exact top-16 -> vote.
// Unpacks 4B entries (value = bf16 hi bits; idx = chunk row0 + local).
// Self-check: overflow or <16 survivors -> set flag (triggers fallback).
// ---------------------------------------------------------------------------
__global__ __launch_bounds__(64) void gather_vote_kernel(
    const float* __restrict__ pdb,
    const unsigned* __restrict__ seg_g, const unsigned* __restrict__ cnt_g,
    int* __restrict__ out_label, float* __restrict__ out_s, int* __restrict__ flag)
{
  __shared__ float    cv[NCH*CAPQ];   // 2560
  __shared__ unsigned ci[NCH*CAPQ];
  const int q    = (int)blockIdx.x;
  const int lane = (int)threadIdx.x;

  bool over = false;
  int tot = 0;
  #pragma unroll
  for (int h = 0; h < NCH/64; ++h) {
    const int c = h*64 + lane;
    const int cnt = (int)cnt_g[q*NCH + c];
    over |= (cnt > CAPQ);
    const int nc = min(cnt, CAPQ);
    tot += nc;
    const int r0c = chunk_row0(c);
    const unsigned* src = seg_g + (size_t)(q*NCH + c)*CAPQ;
    for (int j = 0; j < CAPQ; ++j) {
      float v = NEGF; unsigned idx = 0u;
      if (j < nc) {
        const unsigned e = src[j];
        v = __uint_as_float(e & 0xFFFF0000u);   // bf16 value in high bits
        idx = (unsigned)(r0c + (int)(e & 0xFFFFu));
      }
      cv[c*CAPQ + j] = v;
      ci[c*CAPQ + j] = idx;
    }
  }
  #pragma unroll
  for (int off = 32; off >= 1; off >>= 1) tot += __shfl_xor(tot, off);
  __syncthreads();

  float topv[TK]; int topid[TK];
  #pragma unroll
  for (int r = 0; r < TK; ++r) {
    float bv = NEGF; int bp = -1;
    #pragma unroll 4
    for (int j = 0; j < (NCH*CAPQ)/64; ++j) {
      const int p = j*64 + lane;
      const float v = cv[p];
      if (v > bv) { bv = v; bp = p; }
    }
    #pragma unroll
    for (int off = 32; off >= 1; off >>= 1) {
      const float ov = __shfl_xor(bv, off);
      const int   op = __shfl_xor(bp, off);
      if (ov > bv || (ov == bv && ((unsigned)op < (unsigned)bp))) { bv = ov; bp = op; }
    }
    topv[r] = bv;
    int id = -2;
    if (bp >= 0 && bv > NEGF) id = (int)pdb[(size_t)ci[bp]*PDBW + CDIM];
    topid[r] = id;
    if (lane == 0 && bp >= 0) cv[bp] = NEGF;
    __syncthreads();
  }

  if (lane == 0) {
    bool mk[TK];
    int nvalid = 0;
    #pragma unroll
    for (int i = 0; i < TK; ++i) {
      mk[i] = (topv[i] >= MIN_SIM_C) && (topid[i] >= 0);
      nvalid += mk[i] ? 1 : 0;
    }
    int maj = 0, majid = 0x7fffffff;
    for (int i = 0; i < TK; ++i) {
      if (!mk[i]) continue;
      int c = 0;
      for (int j = 0; j < TK; ++j) c += (mk[j] && topid[j] == topid[i]) ? 1 : 0;
      if (c > maj || (c == maj && topid[i] < majid)) { maj = c; majid = topid[i]; }
    }
    const float ratio = (float)maj / fmaxf((float)nvalid, 1.0f);
    const bool valid = (maj > 0) && (ratio >= MIN_VOTES_C);
    const int label = valid ? majid : -1;
    float s = 0.f;
    #pragma unroll
    for (int i = 0; i < TK; ++i)
      if (mk[i] && topid[i] == label) s = fmaxf(s, topv[i]);
    out_label[q] = label;
    out_s[q]     = s;
  }
  const bool bad = (__ballot(over) != 0ull) || (tot < TK);
  if (lane == 0 && bad) atomicOr(flag, 1);
}

// ---------------------------------------------------------------------------
// Fallback stage 1 (round-1, proven): gated on flag
// ---------------------------------------------------------------------------
__global__ __launch_bounds__(256, 2) void sims_topk1_kernel(
    const float* __restrict__ qd, const float* __restrict__ pdb,
    float* __restrict__ cand_val, unsigned int* __restrict__ cand_idx,
    const int* __restrict__ gate)
{
  if (gate && *gate == 0) return;
  __shared__ __align__(16) short db_lds[128 * 264];
  float* sims = (float*)db_lds;

  const int tid  = (int)threadIdx.x;
  const int lane = tid & 63;
  const int wv   = tid >> 6;
  const int cid   = (int)blockIdx.x;
  const int mtile = (int)blockIdx.y;

  bf16x8 aq[2][8];
  {
    const int l15 = lane & 15;
    const int kb  = (lane >> 4) << 3;
    #pragma unroll
    for (int fm = 0; fm < 2; ++fm) {
      const int row = mtile*128 + wv*32 + fm*16 + l15;
      #pragma unroll
      for (int kk = 0; kk < 8; ++kk) {
        const float* p = qd + (size_t)row*CDIM + kk*32 + kb;
        float4 x0 = *(const float4*)p;
        float4 x1 = *(const float4*)(p + 4);
        bf16x8 a;
        a[0]=f2bf(x0.x); a[1]=f2bf(x0.y); a[2]=f2bf(x0.z); a[3]=f2bf(x0.w);
        a[4]=f2bf(x1.x); a[5]=f2bf(x1.y); a[6]=f2bf(x1.z); a[7]=f2bf(x1.w);
        aq[fm][kk] = a;
      }
    }
  }

  float    tv[TK];
  unsigned ti[TK];
  #pragma unroll
  for (int i = 0; i < TK; ++i) { tv[i] = NEGF; ti[i] = 0u; }
  float minv = NEGF; int minp = 0;

  const int g0chunk = cid * 4096;
  const int q_l  = tid & 127;
  const int half = tid >> 7;

  for (int s = 0; s < 32; ++s) {
    const int g0 = g0chunk + s*128;
    {
      const int rb = tid >> 6;
      const int c4 = (tid & 63) << 2;
      for (int i = 0; i < 32; ++i) {
        const int rl = i*4 + rb;
        const int g  = g0 + rl;
        float v0, v1, v2, v3;
        if (g < NDB) {
          const float* p = pdb + (size_t)g*PDBW + c4;
          v0 = p[0]; v1 = p[1]; v2 = p[2]; v3 = p[3];
        } else { v0 = v1 = v2 = v3 = 0.f; }
        short* d = &db_lds[rl*264 + c4];
        d[0]=f2bf(v0); d[1]=f2bf(v1); d[2]=f2bf(v2); d[3]=f2bf(v3);
      }
    }
    __syncthreads();

    f32x4 acc[2][8];
    #pragma unroll
    for (int fm = 0; fm < 2; ++fm)
      #pragma unroll
      for (int fn = 0; fn < 8; ++fn)
        acc[fm][fn] = (f32x4){0.f, 0.f, 0.f, 0.f};
    {
      const int l15 = lane & 15;
      const int kb  = (lane >> 4) << 3;
      #pragma unroll
      for (int kk = 0; kk < 8; ++kk) {
        bf16x8 b[8];
        #pragma unroll
        for (int fn = 0; fn < 8; ++fn)
          b[fn] = *(const bf16x8*)&db_lds[(fn*16 + l15)*264 + kk*32 + kb];
        #pragma unroll
        for (int fn = 0; fn < 8; ++fn) {
          acc[0][fn] = __builtin_amdgcn_mfma_f32_16x16x32_bf16(aq[0][kk], b[fn], acc[0][fn], 0, 0, 0);
          acc[1][fn] = __builtin_amdgcn_mfma_f32_16x16x32_bf16(aq[1][kk], b[fn], acc[1][fn], 0, 0, 0);
        }
      }
    }
    __syncthreads();

    {
      const int colb = lane & 15;
      const int rowb = (lane >> 4) << 2;
      #pragma unroll
      for (int fm = 0; fm < 2; ++fm)
        #pragma unroll
        for (int fn = 0; fn < 8; ++fn)
          #pragma unroll
          for (int j = 0; j < 4; ++j)
            sims[(wv*32 + fm*16 + rowb + j)*129 + fn*16 + colb] = acc[fm][fn][j];
    }
    __syncthreads();

    {
      const int cb = half * 64;
      #pragma unroll 4
      for (int c = 0; c < 64; ++c) {
        const int colc = cb + c;
        const float v = sims[q_l*129 + colc];
        const int g = g0 + colc;
        if (v > minv && g < NDB) {
          #pragma unroll
          for (int i = 0; i < TK; ++i) if (i == minp) { tv[i] = v; ti[i] = (unsigned)g; }
          minv = tv[0]; minp = 0;
          #pragma unroll
          for (int i = 1; i < TK; ++i) if (tv[i] < minv) { minv = tv[i]; minp = i; }
        }
      }
    }
    __syncthreads();
  }

  {
    const int qg = mtile*128 + q_l;
    float*    pv = cand_val + ((size_t)qg*NCHUNK1 + cid)*32 + half*TK;
    unsigned* pi = cand_idx + ((size_t)qg*NCHUNK1 + cid)*32 + half*TK;
    #pragma unroll
    for (int i = 0; i < TK; ++i) { pv[i] = tv[i]; pi[i] = ti[i]; }
  }
}

// ---------------------------------------------------------------------------
// Fallback stage 2 (round-1, proven): gated on flag
// ---------------------------------------------------------------------------
template<int CPQ>
__global__ __launch_bounds__(64) void merge_vote_kernel(
    const float* __restrict__ pdb,
    const float* __restrict__ cand_val, const unsigned* __restrict__ cand_idx,
    int* __restrict__ out_label, float* __restrict__ out_s,
    const int* __restrict__ gate)
{
  if (gate && *gate == 0) return;
  __shared__ float    cv[CPQ];
  __shared__ unsigned ci[CPQ];
  const int q    = (int)blockIdx.x;
  const int lane = (int)threadIdx.x;

  for (int j = lane; j < CPQ; j += 64) {
    cv[j] = cand_val[(size_t)q*CPQ + j];
    ci[j] = cand_idx[(size_t)q*CPQ + j];
  }
  __syncthreads();

  float topv[TK]; int topid[TK];
  #pragma unroll
  for (int r = 0; r < TK; ++r) {
    float bv = NEGF; int bp = -1;
    for (int j = lane; j < CPQ; j += 64) {
      const float v = cv[j];
      if (v > bv) { bv = v; bp = j; }
    }
    #pragma unroll
    for (int off = 32; off >= 1; off >>= 1) {
      const float ov = __shfl_xor(bv, off);
      const int   op = __shfl_xor(bp, off);
      if (ov > bv || (ov == bv && ((unsigned)op < (unsigned)bp))) { bv = ov; bp = op; }
    }
    topv[r] = bv;
    int id = -2;
    if (bp >= 0 && bv > NEGF) id = (int)pdb[(size_t)ci[bp]*PDBW + CDIM];
    topid[r] = id;
    if (lane == 0 && bp >= 0) cv[bp] = NEGF;
    __syncthreads();
  }

  if (lane == 0) {
    bool mk[TK];
    int nvalid = 0;
    #pragma unroll
    for (int i = 0; i < TK; ++i) {
      mk[i] = (topv[i] >= MIN_SIM_C) && (topid[i] >= 0);
      nvalid += mk[i] ? 1 : 0;
    }
    int maj = 0, majid = 0x7fffffff;
    for (int i = 0; i < TK; ++i) {
      if (!mk[i]) continue;
      int c = 0;
      for (int j = 0; j < TK; ++j) c += (mk[j] && topid[j] == topid[i]) ? 1 : 0;
      if (c > maj || (c == maj && topid[i] < majid)) { maj = c; majid = topid[i]; }
    }
    const float ratio = (float)maj / fmaxf((float)nvalid, 1.0f);
    const bool valid = (maj > 0) && (ratio >= MIN_VOTES_C);
    const int label = valid ? majid : -1;
    float s = 0.f;
    #pragma unroll
    for (int i = 0; i < TK; ++i)
      if (mk[i] && topid[i] == label) s = fmaxf(s, topv[i]);
    out_label[q] = label;
    out_s[q]     = s;
  }
}

// ---------------------------------------------------------------------------
// Stage 3: overlap removal + final outputs
// ---------------------------------------------------------------------------
__device__ __forceinline__ bool finitef(float v) {
  return ((__float_as_uint(v) >> 23) & 0xffu) != 0xffu;
}

__global__ __launch_bounds__(64) void finalize_kernel(
    const float* __restrict__ boxes, const int* __restrict__ labels,
    const float* __restrict__ svals, float* __restrict__ out)
{
  const int x    = (int)blockIdx.x;
  const int lane = (int)threadIdx.x;
  const int lx = labels[x];
  const float bx1 = boxes[x*4+0], by1 = boxes[x*4+1];
  const float bx2 = boxes[x*4+2], by2 = boxes[x*4+3];
  const float ax = (bx2 - bx1) * (by2 - by1);

  bool flag = false;
  if (lx >= 0) {
    for (int y = lane; y < QN; y += 64) {
      if (y == x) continue;
      if (labels[y] != lx) continue;
      const float c1 = boxes[y*4+0], c2 = boxes[y*4+1];
      const float c3 = boxes[y*4+2], c4 = boxes[y*4+3];
      const float ay = (c3 - c1) * (c4 - c2);
      const float xi1 = fmaxf(bx1, c1), yi1 = fmaxf(by1, c2);
      const float xi2 = fminf(bx2, c3), yi2 = fminf(by2, c4);
      const float inter = fmaxf(xi2 - xi1, 0.f) * fmaxf(yi2 - yi1, 0.f);
      const float asmall = fminf(ax, ay);
      const float ov = (asmall > 0.f) ? inter / fmaxf(asmall, 1e-12f) : 0.f;
      if (ov >= 0.5f && ay <= ax) flag = true;
    }
  }
  const bool removed = (__ballot(flag) != 0ull);
  const int label = removed ? -1 : lx;
  const float s = svals[x];
  const bool fin = finitef(s) && finitef(bx1) && finitef(by1) && finitef(bx2) && finitef(by2);
  const bool valid = (label >= 0) && fin;

  if (lane == 0) {
    out[4096 + x] = valid ? s : 0.f;
    out[5120 + x] = (float)(valid ? label : -1);
  }
  if (lane < 4) out[x*4 + lane] = boxes[x*4 + lane];
}

// ---------------------------------------------------------------------------
extern "C" void kernel_launch(void* const* d_in, const int* in_sizes, int n_in,
                              void* d_out, int out_size, void* d_ws, size_t ws_size,
                              hipStream_t stream)
{
  const float* boxes = (const float*)d_in[0];
  const float* qd    = (const float*)d_in[1];
  const float* pdb   = (const float*)d_in[2];
  float* out = (float*)d_out;
  char* ws = (char*)d_ws;

  const size_t db_bytes  = (size_t)NDB_PAD * 256;             //  51,216,384 (fp8)
  const size_t seg_bytes = (size_t)QN * NCH * CAPQ * 4;       //  10,485,760
  const size_t cnt_bytes = (size_t)QN * NCH * 4;              //   1,048,576
  const size_t c1_bytes  = (size_t)QN * CPQ1 * 8;             //  12,845,056 (fallback, aliases seg+cnt)
  const size_t A_bytes   = (seg_bytes + cnt_bytes > c1_bytes) ? seg_bytes + cnt_bytes : c1_bytes;
  const size_t need = db_bytes + A_bytes + (size_t)QN*8 + 64;

  if (ws_size >= need) {
    unsigned char* dbb = (unsigned char*)ws;
    char* A = ws + db_bytes;
    unsigned* seg_g = (unsigned*)A;
    unsigned* cnt_g = (unsigned*)(A + seg_bytes);
    float*    cand_val = (float*)A;
    unsigned* cand_idx = (unsigned*)(A + (size_t)QN*CPQ1*4);
    int*      labels   = (int*)(ws + db_bytes + A_bytes);
    float*    svals    = (float*)(ws + db_bytes + A_bytes + (size_t)QN*4);
    int*      flag     = (int*)(ws + db_bytes + A_bytes + (size_t)QN*8);

    hipLaunchKernelGGL(convert_db_kernel, dim3(2048), dim3(256), 0, stream, pdb, dbb, flag);
    hipLaunchKernelGGL(sims_filter_kernel, dim3(NCH, 2), dim3(512), 0, stream,
                       qd, dbb, seg_g, cnt_g);
    hipLaunchKernelGGL(gather_vote_kernel, dim3(QN), dim3(64), 0, stream,
                       pdb, seg_g, cnt_g, labels, svals, flag);
    hipLaunchKernelGGL(sims_topk1_kernel, dim3(NCHUNK1, 8), dim3(256), 0, stream,
                       qd, pdb, cand_val, cand_idx, flag);
    hipLaunchKernelGGL((merge_vote_kernel<CPQ1>), dim3(QN), dim3(64), 0, stream,
                       pdb, cand_val, cand_idx, labels, svals, flag);
    hipLaunchKernelGGL(finalize_kernel, dim3(QN), dim3(64), 0, stream,
                       boxes, labels, svals, out);
  } else {
    const size_t n1 = (size_t)QN * CPQ1;
    float*    cand_val = (float*)ws;
    unsigned* cand_idx = (unsigned*)(ws + n1*4);
    int*      labels   = (int*)(ws + n1*8);
    float*    svals    = (float*)(ws + n1*8 + (size_t)QN*4);

    hipLaunchKernelGGL(sims_topk1_kernel, dim3(NCHUNK1, 8), dim3(256), 0, stream,
                       qd, pdb, cand_val, cand_idx, (const int*)nullptr);
    hipLaunchKernelGGL((merge_vote_kernel<CPQ1>), dim3(QN), dim3(64), 0, stream,
                       pdb, cand_val, cand_idx, labels, svals, (const int*)nullptr);
    hipLaunchKernelGGL(finalize_kernel, dim3(QN), dim3(64), 0, stream,
                       boxes, labels, svals, out);
  }
}

// Round 16
// 194.592 us; speedup vs baseline: 8.0616x; 1.0360x over previous
//
#include <hip/hip_runtime.h>
#include <hip/hip_bf16.h>

// ---------------- problem constants ----------------
#define QN 1024
#define NDB 200000
#define NDB_PAD 200064        // 3126 subtiles of 64 rows
#define PDBW 257
#define CDIM 256
#define TK 16
#define NEGF (-1e30f)
#define MIN_SIM_C 0.05f
#define MIN_VOTES_C 0.3f

// fast path: 256 chunks x 2 mtiles (512 thr, 8 waves x 64 q); fp8 db in ws
#define NCH 256
#define THETA 0.19f           // P(sim>THETA)=1.18e-3; true 16th-best ~0.236 (fp8 err ~3e-3 -> ~15 sigma)
#define CAPQ 10               // per-(query,chunk) cap (lambda~0.92, P(any over)~3e-5 -> flag+fallback)
// fallback (round-1, proven) path
#define NCHUNK1 49
#define CPQ1 (NCHUNK1*32)

typedef __attribute__((ext_vector_type(8))) short bf16x8;
typedef __attribute__((ext_vector_type(4))) float f32x4;
typedef __attribute__((ext_vector_type(8))) int   i32x8;
typedef __attribute__((ext_vector_type(4))) int   i32x4;

__device__ __forceinline__ short f2bf(float f) {
  union { float f; unsigned u; } x; x.f = f;
  unsigned u = x.u;
  return (short)((u + 0x7fffu + ((u >> 16) & 1u)) >> 16);  // RNE
}

__device__ __forceinline__ void async_copy16(const void* gp, void* lp) {
  __builtin_amdgcn_global_load_lds(
      (__attribute__((address_space(1))) void*)gp,
      (__attribute__((address_space(3))) void*)lp, 16, 0, 0);
}

// pack 4 floats -> 4 fp8 e4m3 bytes (same converter feeds A and B, so any
// consistent lane-position->k mapping cancels in the MFMA dot product)
__device__ __forceinline__ unsigned pk_fp8x4(float a, float b, float c, float d) {
  unsigned w = (unsigned)__builtin_amdgcn_cvt_pk_fp8_f32(a, b, 0, false);
  w = (unsigned)__builtin_amdgcn_cvt_pk_fp8_f32(c, d, (int)w, true);
  return w;
}

// chunk geometry: 3126 subtiles over 256 chunks (0..53 have 13, rest 12)
__device__ __forceinline__ int chunk_nsub(int c) { return 12 + (c < 54 ? 1 : 0); }
__device__ __forceinline__ int chunk_row0(int c) { return (12*c + (c < 54 ? c : 54)) << 6; }

// ---------------------------------------------------------------------------
// Kernel 0: pdb fp32 -> fp8 e4m3, PRE-SWIZZLED global layout (8B piece
// p -> p ^ ((r&15)<<1), matching the filter's XOR'd ds_read), zero-pad rows.
// Linear global_load_lds staging then preserves the swizzle (both-sides rule).
// Also zeroes the fallback flag. (Proven R6-R8, R15.)
// ---------------------------------------------------------------------------
__global__ __launch_bounds__(256) void convert_db_kernel(
    const float* __restrict__ pdb, unsigned char* __restrict__ dbb,
    int* __restrict__ flag)
{
  if (blockIdx.x == 0 && threadIdx.x == 0) *flag = 0;
  const int wv = (int)threadIdx.x >> 6, lane = (int)threadIdx.x & 63;
  for (int r = (int)blockIdx.x*4 + wv; r < NDB_PAD; r += (int)gridDim.x*4) {
    unsigned pack = 0u;
    if (r < NDB) {
      const float* p = pdb + (size_t)r*PDBW + lane*4;
      pack = pk_fp8x4(p[0], p[1], p[2], p[3]);
    }
    const int piece = lane >> 1;                       // 8B piece index 0..31
    const int ps    = piece ^ ((r & 15) << 1);         // == 16B-pair ^ (r&15)
    *(unsigned*)(dbb + (size_t)r*256 + ps*8 + (lane & 1)*4) = pack;
  }
}

// ---------------------------------------------------------------------------
// Kernel 1: MX-fp8 (K=128, unit scale) MFMA sims + register theta-filter +
// wave-private LDS survivor lists (packed 4B entries: bf16val<<16 | local idx).
// grid (256 chunks, 2 mtiles) = 512 blocks (2/CU, 16 waves/CU), 512 thr
// (8 waves x 64 q). Staging via global_load_lds, wave-uniform-base + lane*16
// (R15-proven). fn-SPLIT accumulator keeps live ~110-130 regs.
// LAUNCH_BOUNDS (512,1): R15's (512,4) clamped the allocator to 64 VGPR ->
// ~38MB scratch spill (WRITE_SIZE 44MB) and MfmaUtil 17%; R13's (512,1) with
// a same-size live set allocated 92 regs, ZERO spill. One barrier per
// 64-row subtile (R7-proven rotation). LDS 54KB -> 2 blocks/CU.
// ---------------------------------------------------------------------------
__global__ __launch_bounds__(512, 1) void sims_filter_kernel(
    const float* __restrict__ qd, const unsigned char* __restrict__ dbb,
    unsigned int* __restrict__ seg_g, unsigned int* __restrict__ cnt_g)
{
  __shared__ __align__(16) char db_lds[2][64 * 256];   // 32768 B (fp8, swizzled)
  __shared__ unsigned seg_lds[8][64][CAPQ];            // 20480 B (wave-private)
  __shared__ int lcnt[8][64];                          // 2048 B (wave-private)

  const int tid  = (int)threadIdx.x;
  const int lane = tid & 63;
  const int wv   = tid >> 6;          // 0..7
  const int cid  = (int)blockIdx.x;   // 0..255
  const int mt   = (int)blockIdx.y;   // 0..1
  const int nsub = chunk_nsub(cid);
  const int row0 = chunk_row0(cid);

  lcnt[wv][lane] = 0;   // wave-private, no barrier needed

  const int l15  = lane & 15;
  const int egrp = lane >> 4;         // k-chunk group 0..3 (32 k each)
  const int rowb = egrp << 2;
  const int colb = l15;

  // ---- Q fragments: fp32 -> fp8 packed i32x8; wave wv owns 64 queries ----
  i32x8 aq[4][2];
  {
    #pragma unroll
    for (int fm = 0; fm < 4; ++fm) {
      const float* qrow = qd + (size_t)(mt*512 + wv*64 + fm*16 + l15)*CDIM;
      #pragma unroll
      for (int kk = 0; kk < 2; ++kk) {
        const float* p = qrow + kk*128 + egrp*32;
        i32x8 a;
        #pragma unroll
        for (int d = 0; d < 8; ++d) {
          float4 x = *(const float4*)(p + d*4);
          a[d] = (int)pk_fp8x4(x.x, x.y, x.z, x.w);
        }
        aq[fm][kk] = a;
      }
    }
  }

  const char* dbbase = (const char*)dbb;
  // HW rule: per-lane lds addr must be wave-uniform-base + lane*16.
  // Wave wv owns bytes [wv*2048, wv*2048+2048) of the 16KB tile: 2 batches.
#define STAGE(bufi, tile) do { \
    const char* _src = dbbase + ((size_t)(row0 + (tile)*64) * 256) + wv*2048 + lane*16; \
    char* _dst = (char*)db_lds[(bufi)] + wv*2048 + lane*16; \
    async_copy16(_src,        _dst); \
    async_copy16(_src + 1024, _dst + 1024); \
  } while (0)

  STAGE(0, 0);   // prologue: tile 0 loads in flight

  for (int s = 0; s < nsub; ++s) {
    // tile s's loads were issued a full iteration ago -> this drain is cheap
    asm volatile("s_waitcnt vmcnt(0)" ::: "memory");
    __builtin_amdgcn_sched_barrier(0);
    __builtin_amdgcn_s_barrier();       // tile s visible; tile s-1 reads drained
    __builtin_amdgcn_sched_barrier(0);

    // issue next tile into the other buffer NOW (overwrites tile s-1 -- safe;
    // DMA latency hides under the MFMA+filter phases below)
    if (s + 1 < nsub) STAGE((s + 1) & 1, s + 1);

    const char* dbt = (const char*)db_lds[s & 1];
    // ---- fn-split: two halves, each MFMA (acc[4][2]) then filter ----
    #pragma unroll
    for (int h = 0; h < 2; ++h) {
      f32x4 acc[4][2];
      #pragma unroll
      for (int fm = 0; fm < 4; ++fm)
        #pragma unroll
        for (int fnl = 0; fnl < 2; ++fnl)
          acc[fm][fnl] = (f32x4){0.f, 0.f, 0.f, 0.f};

      __builtin_amdgcn_s_setprio(1);
      #pragma unroll
      for (int kk = 0; kk < 2; ++kk) {
        #pragma unroll
        for (int fnl = 0; fnl < 2; ++fnl) {
          const int fn = h*2 + fnl;
          const char* rowp = dbt + (fn*16 + l15)*256;
          const int mbase = kk*8 + egrp*2;
          i32x4 lo = *(const i32x4*)(rowp + (((mbase    ) ^ l15) << 4));
          i32x4 hi = *(const i32x4*)(rowp + (((mbase + 1) ^ l15) << 4));
          i32x8 b = __builtin_shufflevector(lo, hi, 0, 1, 2, 3, 4, 5, 6, 7);
          #pragma unroll
          for (int fm = 0; fm < 4; ++fm)
            acc[fm][fnl] = __builtin_amdgcn_mfma_scale_f32_16x16x128_f8f6f4(
                aq[fm][kk], b, acc[fm][fnl],
                0 /*fmtA=fp8*/, 0 /*fmtB=fp8*/,
                0, 0x7F7F7F7Fu /*scaleA=1.0*/, 0, 0x7F7F7F7Fu /*scaleB=1.0*/);
        }
      }
      __builtin_amdgcn_s_setprio(0);

      // theta-filter; packed 4B append (value bf16 hi | chunk-local idx lo)
      #pragma unroll
      for (int fm = 0; fm < 4; ++fm)
        #pragma unroll
        for (int fnl = 0; fnl < 2; ++fnl) {
          const f32x4 a = acc[fm][fnl];
          const float m = fmaxf(fmaxf(a[0], a[1]), fmaxf(a[2], a[3]));
          if (m > THETA) {
            #pragma unroll
            for (int j = 0; j < 4; ++j) {
              if (a[j] > THETA) {
                const int ql = fm*16 + rowb + j;
                const int slot = atomicAdd(&lcnt[wv][ql], 1);
                if (slot < CAPQ) {
                  const unsigned v16 = (unsigned)(unsigned short)f2bf(a[j]);
                  const unsigned loc = (unsigned)(s*64 + (h*2 + fnl)*16 + colb);
                  seg_lds[wv][ql][slot] = (v16 << 16) | loc;
                }
              }
            }
          }
        }
    }

    // drain own ds ops before the next barrier: buffer rotation hazard-free
    asm volatile("s_waitcnt lgkmcnt(0)" ::: "memory");
    __builtin_amdgcn_sched_barrier(0);
  }
#undef STAGE

  // ---- flush wave-private survivor lists to global (lane == wave-local q) ----
  {
    const int cnt = lcnt[wv][lane];
    const int qg = mt*512 + wv*64 + lane;
    cnt_g[qg*NCH + cid] = (unsigned)cnt;
    const int nc = min(cnt, CAPQ);
    unsigned* dst = seg_g + (size_t)(qg*NCH + cid)*CAPQ;
    for (int j = 0; j < nc; ++j) dst[j] = seg_lds[wv][lane][j];
  }
}

// ---------------------------------------------------------------------------
// Kernel 2: per-query gather of survivors -> exact top-16 -> vote.
// Unpacks 4B entries (value = bf16 hi bits; idx = chunk row0 + local).
// Self-check: overflow or <16 survivors -> set flag (triggers fallback).
// ---------------------------------------------------------------------------
__global__ __launch_bounds__(64) void gather_vote_kernel(
    const float* __restrict__ pdb,
    const unsigned* __restrict__ seg_g, const unsigned* __restrict__ cnt_g,
    int* __restrict__ out_label, float* __restrict__ out_s, int* __restrict__ flag)
{
  __shared__ float    cv[NCH*CAPQ];   // 2560
  __shared__ unsigned ci[NCH*CAPQ];
  const int q    = (int)blockIdx.x;
  const int lane = (int)threadIdx.x;

  bool over = false;
  int tot = 0;
  #pragma unroll
  for (int h = 0; h < NCH/64; ++h) {
    const int c = h*64 + lane;
    const int cnt = (int)cnt_g[q*NCH + c];
    over |= (cnt > CAPQ);
    const int nc = min(cnt, CAPQ);
    tot += nc;
    const int r0c = chunk_row0(c);
    const unsigned* src = seg_g + (size_t)(q*NCH + c)*CAPQ;
    for (int j = 0; j < CAPQ; ++j) {
      float v = NEGF; unsigned idx = 0u;
      if (j < nc) {
        const unsigned e = src[j];
        v = __uint_as_float(e & 0xFFFF0000u);   // bf16 value in high bits
        idx = (unsigned)(r0c + (int)(e & 0xFFFFu));
      }
      cv[c*CAPQ + j] = v;
      ci[c*CAPQ + j] = idx;
    }
  }
  #pragma unroll
  for (int off = 32; off >= 1; off >>= 1) tot += __shfl_xor(tot, off);
  __syncthreads();

  float topv[TK]; int topid[TK];
  #pragma unroll
  for (int r = 0; r < TK; ++r) {
    float bv = NEGF; int bp = -1;
    #pragma unroll 4
    for (int j = 0; j < (NCH*CAPQ)/64; ++j) {
      const int p = j*64 + lane;
      const float v = cv[p];
      if (v > bv) { bv = v; bp = p; }
    }
    #pragma unroll
    for (int off = 32; off >= 1; off >>= 1) {
      const float ov = __shfl_xor(bv, off);
      const int   op = __shfl_xor(bp, off);
      if (ov > bv || (ov == bv && ((unsigned)op < (unsigned)bp))) { bv = ov; bp = op; }
    }
    topv[r] = bv;
    int id = -2;
    if (bp >= 0 && bv > NEGF) id = (int)pdb[(size_t)ci[bp]*PDBW + CDIM];
    topid[r] = id;
    if (lane == 0 && bp >= 0) cv[bp] = NEGF;
    __syncthreads();
  }

  if (lane == 0) {
    bool mk[TK];
    int nvalid = 0;
    #pragma unroll
    for (int i = 0; i < TK; ++i) {
      mk[i] = (topv[i] >= MIN_SIM_C) && (topid[i] >= 0);
      nvalid += mk[i] ? 1 : 0;
    }
    int maj = 0, majid = 0x7fffffff;
    for (int i = 0; i < TK; ++i) {
      if (!mk[i]) continue;
      int c = 0;
      for (int j = 0; j < TK; ++j) c += (mk[j] && topid[j] == topid[i]) ? 1 : 0;
      if (c > maj || (c == maj && topid[i] < majid)) { maj = c; majid = topid[i]; }
    }
    const float ratio = (float)maj / fmaxf((float)nvalid, 1.0f);
    const bool valid = (maj > 0) && (ratio >= MIN_VOTES_C);
    const int label = valid ? majid : -1;
    float s = 0.f;
    #pragma unroll
    for (int i = 0; i < TK; ++i)
      if (mk[i] && topid[i] == label) s = fmaxf(s, topv[i]);
    out_label[q] = label;
    out_s[q]     = s;
  }
  const bool bad = (__ballot(over) != 0ull) || (tot < TK);
  if (lane == 0 && bad) atomicOr(flag, 1);
}

// ---------------------------------------------------------------------------
// Fallback stage 1 (round-1, proven): gated on flag
// ---------------------------------------------------------------------------
__global__ __launch_bounds__(256, 2) void sims_topk1_kernel(
    const float* __restrict__ qd, const float* __restrict__ pdb,
    float* __restrict__ cand_val, unsigned int* __restrict__ cand_idx,
    const int* __restrict__ gate)
{
  if (gate && *gate == 0) return;
  __shared__ __align__(16) short db_lds[128 * 264];
  float* sims = (float*)db_lds;

  const int tid  = (int)threadIdx.x;
  const int lane = tid & 63;
  const int wv   = tid >> 6;
  const int cid   = (int)blockIdx.x;
  const int mtile = (int)blockIdx.y;

  bf16x8 aq[2][8];
  {
    const int l15 = lane & 15;
    const int kb  = (lane >> 4) << 3;
    #pragma unroll
    for (int fm = 0; fm < 2; ++fm) {
      const int row = mtile*128 + wv*32 + fm*16 + l15;
      #pragma unroll
      for (int kk = 0; kk < 8; ++kk) {
        const float* p = qd + (size_t)row*CDIM + kk*32 + kb;
        float4 x0 = *(const float4*)p;
        float4 x1 = *(const float4*)(p + 4);
        bf16x8 a;
        a[0]=f2bf(x0.x); a[1]=f2bf(x0.y); a[2]=f2bf(x0.z); a[3]=f2bf(x0.w);
        a[4]=f2bf(x1.x); a[5]=f2bf(x1.y); a[6]=f2bf(x1.z); a[7]=f2bf(x1.w);
        aq[fm][kk] = a;
      }
    }
  }

  float    tv[TK];
  unsigned ti[TK];
  #pragma unroll
  for (int i = 0; i < TK; ++i) { tv[i] = NEGF; ti[i] = 0u; }
  float minv = NEGF; int minp = 0;

  const int g0chunk = cid * 4096;
  const int q_l  = tid & 127;
  const int half = tid >> 7;

  for (int s = 0; s < 32; ++s) {
    const int g0 = g0chunk + s*128;
    {
      const int rb = tid >> 6;
      const int c4 = (tid & 63) << 2;
      for (int i = 0; i < 32; ++i) {
        const int rl = i*4 + rb;
        const int g  = g0 + rl;
        float v0, v1, v2, v3;
        if (g < NDB) {
          const float* p = pdb + (size_t)g*PDBW + c4;
          v0 = p[0]; v1 = p[1]; v2 = p[2]; v3 = p[3];
        } else { v0 = v1 = v2 = v3 = 0.f; }
        short* d = &db_lds[rl*264 + c4];
        d[0]=f2bf(v0); d[1]=f2bf(v1); d[2]=f2bf(v2); d[3]=f2bf(v3);
      }
    }
    __syncthreads();

    f32x4 acc[2][8];
    #pragma unroll
    for (int fm = 0; fm < 2; ++fm)
      #pragma unroll
      for (int fn = 0; fn < 8; ++fn)
        acc[fm][fn] = (f32x4){0.f, 0.f, 0.f, 0.f};
    {
      const int l15 = lane & 15;
      const int kb  = (lane >> 4) << 3;
      #pragma unroll
      for (int kk = 0; kk < 8; ++kk) {
        bf16x8 b[8];
        #pragma unroll
        for (int fn = 0; fn < 8; ++fn)
          b[fn] = *(const bf16x8*)&db_lds[(fn*16 + l15)*264 + kk*32 + kb];
        #pragma unroll
        for (int fn = 0; fn < 8; ++fn) {
          acc[0][fn] = __builtin_amdgcn_mfma_f32_16x16x32_bf16(aq[0][kk], b[fn], acc[0][fn], 0, 0, 0);
          acc[1][fn] = __builtin_amdgcn_mfma_f32_16x16x32_bf16(aq[1][kk], b[fn], acc[1][fn], 0, 0, 0);
        }
      }
    }
    __syncthreads();

    {
      const int colb = lane & 15;
      const int rowb = (lane >> 4) << 2;
      #pragma unroll
      for (int fm = 0; fm < 2; ++fm)
        #pragma unroll
        for (int fn = 0; fn < 8; ++fn)
          #pragma unroll
          for (int j = 0; j < 4; ++j)
            sims[(wv*32 + fm*16 + rowb + j)*129 + fn*16 + colb] = acc[fm][fn][j];
    }
    __syncthreads();

    {
      const int cb = half * 64;
      #pragma unroll 4
      for (int c = 0; c < 64; ++c) {
        const int colc = cb + c;
        const float v = sims[q_l*129 + colc];
        const int g = g0 + colc;
        if (v > minv && g < NDB) {
          #pragma unroll
          for (int i = 0; i < TK; ++i) if (i == minp) { tv[i] = v; ti[i] = (unsigned)g; }
          minv = tv[0]; minp = 0;
          #pragma unroll
          for (int i = 1; i < TK; ++i) if (tv[i] < minv) { minv = tv[i]; minp = i; }
        }
      }
    }
    __syncthreads();
  }

  {
    const int qg = mtile*128 + q_l;
    float*    pv = cand_val + ((size_t)qg*NCHUNK1 + cid)*32 + half*TK;
    unsigned* pi = cand_idx + ((size_t)qg*NCHUNK1 + cid)*32 + half*TK;
    #pragma unroll
    for (int i = 0; i < TK; ++i) { pv[i] = tv[i]; pi[i] = ti[i]; }
  }
}

// ---------------------------------------------------------------------------
// Fallback stage 2 (round-1, proven): gated on flag
// ---------------------------------------------------------------------------
template<int CPQ>
__global__ __launch_bounds__(64) void merge_vote_kernel(
    const float* __restrict__ pdb,
    const float* __restrict__ cand_val, const unsigned* __restrict__ cand_idx,
    int* __restrict__ out_label, float* __restrict__ out_s,
    const int* __restrict__ gate)
{
  if (gate && *gate == 0) return;
  __shared__ float    cv[CPQ];
  __shared__ unsigned ci[CPQ];
  const int q    = (int)blockIdx.x;
  const int lane = (int)threadIdx.x;

  for (int j = lane; j < CPQ; j += 64) {
    cv[j] = cand_val[(size_t)q*CPQ + j];
    ci[j] = cand_idx[(size_t)q*CPQ + j];
  }
  __syncthreads();

  float topv[TK]; int topid[TK];
  #pragma unroll
  for (int r = 0; r < TK; ++r) {
    float bv = NEGF; int bp = -1;
    for (int j = lane; j < CPQ; j += 64) {
      const float v = cv[j];
      if (v > bv) { bv = v; bp = j; }
    }
    #pragma unroll
    for (int off = 32; off >= 1; off >>= 1) {
      const float ov = __shfl_xor(bv, off);
      const int   op = __shfl_xor(bp, off);
      if (ov > bv || (ov == bv && ((unsigned)op < (unsigned)bp))) { bv = ov; bp = op; }
    }
    topv[r] = bv;
    int id = -2;
    if (bp >= 0 && bv > NEGF) id = (int)pdb[(size_t)ci[bp]*PDBW + CDIM];
    topid[r] = id;
    if (lane == 0 && bp >= 0) cv[bp] = NEGF;
    __syncthreads();
  }

  if (lane == 0) {
    bool mk[TK];
    int nvalid = 0;
    #pragma unroll
    for (int i = 0; i < TK; ++i) {
      mk[i] = (topv[i] >= MIN_SIM_C) && (topid[i] >= 0);
      nvalid += mk[i] ? 1 : 0;
    }
    int maj = 0, majid = 0x7fffffff;
    for (int i = 0; i < TK; ++i) {
      if (!mk[i]) continue;
      int c = 0;
      for (int j = 0; j < TK; ++j) c += (mk[j] && topid[j] == topid[i]) ? 1 : 0;
      if (c > maj || (c == maj && topid[i] < majid)) { maj = c; majid = topid[i]; }
    }
    const float ratio = (float)maj / fmaxf((float)nvalid, 1.0f);
    const bool valid = (maj > 0) && (ratio >= MIN_VOTES_C);
    const int label = valid ? majid : -1;
    float s = 0.f;
    #pragma unroll
    for (int i = 0; i < TK; ++i)
      if (mk[i] && topid[i] == label) s = fmaxf(s, topv[i]);
    out_label[q] = label;
    out_s[q]     = s;
  }
}

// ---------------------------------------------------------------------------
// Stage 3: overlap removal + final outputs
// ---------------------------------------------------------------------------
__device__ __forceinline__ bool finitef(float v) {
  return ((__float_as_uint(v) >> 23) & 0xffu) != 0xffu;
}

__global__ __launch_bounds__(64) void finalize_kernel(
    const float* __restrict__ boxes, const int* __restrict__ labels,
    const float* __restrict__ svals, float* __restrict__ out)
{
  const int x    = (int)blockIdx.x;
  const int lane = (int)threadIdx.x;
  const int lx = labels[x];
  const float bx1 = boxes[x*4+0], by1 = boxes[x*4+1];
  const float bx2 = boxes[x*4+2], by2 = boxes[x*4+3];
  const float ax = (bx2 - bx1) * (by2 - by1);

  bool flag = false;
  if (lx >= 0) {
    for (int y = lane; y < QN; y += 64) {
      if (y == x) continue;
      if (labels[y] != lx) continue;
      const float c1 = boxes[y*4+0], c2 = boxes[y*4+1];
      const float c3 = boxes[y*4+2], c4 = boxes[y*4+3];
      const float ay = (c3 - c1) * (c4 - c2);
      const float xi1 = fmaxf(bx1, c1), yi1 = fmaxf(by1, c2);
      const float xi2 = fminf(bx2, c3), yi2 = fminf(by2, c4);
      const float inter = fmaxf(xi2 - xi1, 0.f) * fmaxf(yi2 - yi1, 0.f);
      const float asmall = fminf(ax, ay);
      const float ov = (asmall > 0.f) ? inter / fmaxf(asmall, 1e-12f) : 0.f;
      if (ov >= 0.5f && ay <= ax) flag = true;
    }
  }
  const bool removed = (__ballot(flag) != 0ull);
  const int label = removed ? -1 : lx;
  const float s = svals[x];
  const bool fin = finitef(s) && finitef(bx1) && finitef(by1) && finitef(bx2) && finitef(by2);
  const bool valid = (label >= 0) && fin;

  if (lane == 0) {
    out[4096 + x] = valid ? s : 0.f;
    out[5120 + x] = (float)(valid ? label : -1);
  }
  if (lane < 4) out[x*4 + lane] = boxes[x*4 + lane];
}

// ---------------------------------------------------------------------------
extern "C" void kernel_launch(void* const* d_in, const int* in_sizes, int n_in,
                              void* d_out, int out_size, void* d_ws, size_t ws_size,
                              hipStream_t stream)
{
  const float* boxes = (const float*)d_in[0];
  const float* qd    = (const float*)d_in[1];
  const float* pdb   = (const float*)d_in[2];
  float* out = (float*)d_out;
  char* ws = (char*)d_ws;

  const size_t db_bytes  = (size_t)NDB_PAD * 256;             //  51,216,384 (fp8)
  const size_t seg_bytes = (size_t)QN * NCH * CAPQ * 4;       //  10,485,760
  const size_t cnt_bytes = (size_t)QN * NCH * 4;              //   1,048,576
  const size_t c1_bytes  = (size_t)QN * CPQ1 * 8;             //  12,845,056 (fallback, aliases seg+cnt)
  const size_t A_bytes   = (seg_bytes + cnt_bytes > c1_bytes) ? seg_bytes + cnt_bytes : c1_bytes;
  const size_t need = db_bytes + A_bytes + (size_t)QN*8 + 64;

  if (ws_size >= need) {
    unsigned char* dbb = (unsigned char*)ws;
    char* A = ws + db_bytes;
    unsigned* seg_g = (unsigned*)A;
    unsigned* cnt_g = (unsigned*)(A + seg_bytes);
    float*    cand_val = (float*)A;
    unsigned* cand_idx = (unsigned*)(A + (size_t)QN*CPQ1*4);
    int*      labels   = (int*)(ws + db_bytes + A_bytes);
    float*    svals    = (float*)(ws + db_bytes + A_bytes + (size_t)QN*4);
    int*      flag     = (int*)(ws + db_bytes + A_bytes + (size_t)QN*8);

    hipLaunchKernelGGL(convert_db_kernel, dim3(2048), dim3(256), 0, stream, pdb, dbb, flag);
    hipLaunchKernelGGL(sims_filter_kernel, dim3(NCH, 2), dim3(512), 0, stream,
                       qd, dbb, seg_g, cnt_g);
    hipLaunchKernelGGL(gather_vote_kernel, dim3(QN), dim3(64), 0, stream,
                       pdb, seg_g, cnt_g, labels, svals, flag);
    hipLaunchKernelGGL(sims_topk1_kernel, dim3(NCHUNK1, 8), dim3(256), 0, stream,
                       qd, pdb, cand_val, cand_idx, flag);
    hipLaunchKernelGGL((merge_vote_kernel<CPQ1>), dim3(QN), dim3(64), 0, stream,
                       pdb, cand_val, cand_idx, labels, svals, flag);
    hipLaunchKernelGGL(finalize_kernel, dim3(QN), dim3(64), 0, stream,
                       boxes, labels, svals, out);
  } else {
    const size_t n1 = (size_t)QN * CPQ1;
    float*    cand_val = (float*)ws;
    unsigned* cand_idx = (unsigned*)(ws + n1*4);
    int*      labels   = (int*)(ws + n1*8);
    float*    svals    = (float*)(ws + n1*8 + (size_t)QN*4);

    hipLaunchKernelGGL(sims_topk1_kernel, dim3(NCHUNK1, 8), dim3(256), 0, stream,
                       qd, pdb, cand_val, cand_idx, (const int*)nullptr);
    hipLaunchKernelGGL((merge_vote_kernel<CPQ1>), dim3(QN), dim3(64), 0, stream,
                       pdb, cand_val, cand_idx, labels, svals, (const int*)nullptr);
    hipLaunchKernelGGL(finalize_kernel, dim3(QN), dim3(64), 0, stream,
                       boxes, labels, svals, out);
  }
}

// Round 17
// 166.181 us; speedup vs baseline: 9.4399x; 1.1710x over previous
//
#include <hip/hip_runtime.h>
#include <hip/hip_bf16.h>

// ---------------- problem constants ----------------
#define QN 1024
#define NDB 200000
#define NDB_PAD 200064        // 3126 subtiles of 64 rows
#define PDBW 257
#define CDIM 256
#define TK 16
#define NEGF (-1e30f)
#define MIN_SIM_C 0.05f
#define MIN_VOTES_C 0.3f

// fast path: 128 chunks x 4 mtiles (256 thr, 4 waves x 64 q); fp8 db in ws.
// All chunks have an EVEN subtile count: 0..26 -> 26, 27..127 -> 24 (=3126).
#define NCH 128
#define THETA 0.19f           // P(sim>THETA)=1.18e-3; true 16th-best ~0.236 (fp8 err ~3e-3 -> ~15 sigma)
#define CAPQ 14               // per-(query,chunk) cap (lambda~1.84, P(over)~1e-9/cell)
// fallback (round-1, proven) path
#define NCHUNK1 49
#define CPQ1 (NCHUNK1*32)

typedef __attribute__((ext_vector_type(8))) short bf16x8;
typedef __attribute__((ext_vector_type(4))) float f32x4;
typedef __attribute__((ext_vector_type(8))) int   i32x8;
typedef __attribute__((ext_vector_type(4))) int   i32x4;

__device__ __forceinline__ short f2bf(float f) {
  union { float f; unsigned u; } x; x.f = f;
  unsigned u = x.u;
  return (short)((u + 0x7fffu + ((u >> 16) & 1u)) >> 16);  // RNE
}

__device__ __forceinline__ void async_copy16(const void* gp, void* lp) {
  __builtin_amdgcn_global_load_lds(
      (__attribute__((address_space(1))) void*)gp,
      (__attribute__((address_space(3))) void*)lp, 16, 0, 0);
}

// pack 4 floats -> 4 fp8 e4m3 bytes (same converter feeds A and B, so any
// consistent lane-position->k mapping cancels in the MFMA dot product)
__device__ __forceinline__ unsigned pk_fp8x4(float a, float b, float c, float d) {
  unsigned w = (unsigned)__builtin_amdgcn_cvt_pk_fp8_f32(a, b, 0, false);
  w = (unsigned)__builtin_amdgcn_cvt_pk_fp8_f32(c, d, (int)w, true);
  return w;
}

// chunk geometry: 3126 subtiles over 128 chunks, ALL EVEN:
// chunks 0..26 have 26 subtiles, 27..127 have 24 (27*26 + 101*24 = 3126)
__device__ __forceinline__ int chunk_nsub(int c) { return 24 + (c < 27 ? 2 : 0); }
__device__ __forceinline__ int chunk_row0(int c) { return (24*c + (c < 27 ? 2*c : 54)) << 6; }

// ---------------------------------------------------------------------------
// Kernel 0: pdb fp32 -> fp8 e4m3, PRE-SWIZZLED global layout (8B piece
// p -> p ^ ((r&15)<<1), matching the filter's XOR'd ds_read), zero-pad rows.
// Linear global_load_lds staging then preserves the swizzle (both-sides rule).
// Also zeroes the fallback flag. (Proven R6-R8, R15, R16.)
// ---------------------------------------------------------------------------
__global__ __launch_bounds__(256) void convert_db_kernel(
    const float* __restrict__ pdb, unsigned char* __restrict__ dbb,
    int* __restrict__ flag)
{
  if (blockIdx.x == 0 && threadIdx.x == 0) *flag = 0;
  const int wv = (int)threadIdx.x >> 6, lane = (int)threadIdx.x & 63;
  for (int r = (int)blockIdx.x*4 + wv; r < NDB_PAD; r += (int)gridDim.x*4) {
    unsigned pack = 0u;
    if (r < NDB) {
      const float* p = pdb + (size_t)r*PDBW + lane*4;
      pack = pk_fp8x4(p[0], p[1], p[2], p[3]);
    }
    const int piece = lane >> 1;                       // 8B piece index 0..31
    const int ps    = piece ^ ((r & 15) << 1);         // == 16B-pair ^ (r&15)
    *(unsigned*)(dbb + (size_t)r*256 + ps*8 + (lane & 1)*4) = pack;
  }
}

// ---------------------------------------------------------------------------
// Kernel 1: MX-fp8 (K=128, unit scale) MFMA sims + register theta-filter +
// wave-private LDS survivor lists (packed 4B: bf16val<<16 | chunk-local idx).
// grid (128 chunks, 4 mtiles) = 512 blocks (2/CU), 256 thr (4 WAVES x 64 q).
// TWO 64-row tiles per barrier interval (pair-granularity double buffer over
// 4x16KB bufs) -- exactly R7's proven single-barrier rotation at 2x
// granularity. Rationale (R7/R10/R13/R15 cross-round data): per-barrier-
// iteration cost is ~structure-constant and smallest for 4-wave blocks
// (4.1 us/iter); halving barrier count (24.4 -> 12.2 iters, even-nsub
// chunks so no tail) attacks the measured floor directly.
// Staging: wave-uniform-base + lane*16 DMA (HW rule, R15-proven).
// 256-thr (256,2): 2048/8 waves = 256-reg budget; live ~158 -> NO spill.
// LDS 64+14+1 = 79KB -> 2 blocks/CU (8 waves/CU).
// ---------------------------------------------------------------------------
__global__ __launch_bounds__(256, 2) void sims_filter_kernel(
    const float* __restrict__ qd, const unsigned char* __restrict__ dbb,
    unsigned int* __restrict__ seg_g, unsigned int* __restrict__ cnt_g)
{
  __shared__ __align__(16) char db_lds[4][64 * 256];   // 65536 B (fp8, swizzled)
  __shared__ unsigned seg_lds[4][64][CAPQ];            // 14336 B (wave-private)
  __shared__ int lcnt[4][64];                          // 1024 B (wave-private)

  const int tid  = (int)threadIdx.x;
  const int lane = tid & 63;
  const int wv   = tid >> 6;          // 0..3
  const int cid  = (int)blockIdx.x;   // 0..127
  const int mt   = (int)blockIdx.y;   // 0..3
  const int nit  = chunk_nsub(cid) >> 1;   // 12 or 13 double-iterations
  const int row0 = chunk_row0(cid);

  lcnt[wv][lane] = 0;   // wave-private, no barrier needed

  const int l15  = lane & 15;
  const int egrp = lane >> 4;         // k-chunk group 0..3 (32 k each)
  const int rowb = egrp << 2;
  const int colb = l15;

  // ---- Q fragments: fp32 -> fp8 packed i32x8; wave wv owns 64 queries ----
  i32x8 aq[4][2];
  {
    #pragma unroll
    for (int fm = 0; fm < 4; ++fm) {
      const float* qrow = qd + (size_t)(mt*256 + wv*64 + fm*16 + l15)*CDIM;
      #pragma unroll
      for (int kk = 0; kk < 2; ++kk) {
        const float* p = qrow + kk*128 + egrp*32;
        i32x8 a;
        #pragma unroll
        for (int d = 0; d < 8; ++d) {
          float4 x = *(const float4*)(p + d*4);
          a[d] = (int)pk_fp8x4(x.x, x.y, x.z, x.w);
        }
        aq[fm][kk] = a;
      }
    }
  }

  const char* dbbase = (const char*)dbb;
  // HW rule: per-lane lds addr = wave-uniform-base + lane*16.
  // 256 thr cover a 16KB tile: wave wv owns 4KB = 4x 1024B batches.
#define STAGE(bufi, tile) do { \
    const char* _src = dbbase + ((size_t)(row0 + (tile)*64) * 256) + wv*4096 + lane*16; \
    char* _dst = (char*)db_lds[(bufi)] + wv*4096 + lane*16; \
    async_copy16(_src,        _dst); \
    async_copy16(_src + 1024, _dst + 1024); \
    async_copy16(_src + 2048, _dst + 2048); \
    async_copy16(_src + 3072, _dst + 3072); \
  } while (0)

  // prologue: pair for iteration 0 (tiles 0,1 -> bufs 0,1)
  STAGE(0, 0);
  STAGE(1, 1);

  for (int i = 0; i < nit; ++i) {
    // pair for this iteration was issued one full iteration ago -> cheap wait
    asm volatile("s_waitcnt vmcnt(0)" ::: "memory");
    __builtin_amdgcn_sched_barrier(0);
    __builtin_amdgcn_s_barrier();       // pair i resident; pair i-1 reads drained
    __builtin_amdgcn_sched_barrier(0);

    // stage the pair for iteration i+1 into the bufs freed by this barrier
    // (pair P(i+1) = P(i-1)); its DMA has the whole 2-tile body to land
    const int rp = (i & 1) << 1;        // read bufs: rp, rp+1
    if (i + 1 < nit) {
      const int wp = rp ^ 2;            // write bufs: other pair
      STAGE(wp,     2*(i+1));
      STAGE(wp + 1, 2*(i+1) + 1);
    }

    // ---- two tiles: each MFMA(32x mfma_scale) then theta-filter ----
    #pragma unroll
    for (int t = 0; t < 2; ++t) {
      const char* dbt = (const char*)db_lds[rp + t];
      f32x4 acc[4][4];
      #pragma unroll
      for (int fm = 0; fm < 4; ++fm)
        #pragma unroll
        for (int fn = 0; fn < 4; ++fn)
          acc[fm][fn] = (f32x4){0.f, 0.f, 0.f, 0.f};

      __builtin_amdgcn_s_setprio(1);
      #pragma unroll
      for (int kk = 0; kk < 2; ++kk) {
        #pragma unroll
        for (int fn = 0; fn < 4; ++fn) {
          const char* rowp = dbt + (fn*16 + l15)*256;
          const int mbase = kk*8 + egrp*2;
          i32x4 lo = *(const i32x4*)(rowp + (((mbase    ) ^ l15) << 4));
          i32x4 hi = *(const i32x4*)(rowp + (((mbase + 1) ^ l15) << 4));
          i32x8 b = __builtin_shufflevector(lo, hi, 0, 1, 2, 3, 4, 5, 6, 7);
          #pragma unroll
          for (int fm = 0; fm < 4; ++fm)
            acc[fm][fn] = __builtin_amdgcn_mfma_scale_f32_16x16x128_f8f6f4(
                aq[fm][kk], b, acc[fm][fn],
                0 /*fmtA=fp8*/, 0 /*fmtB=fp8*/,
                0, 0x7F7F7F7Fu /*scaleA=1.0*/, 0, 0x7F7F7F7Fu /*scaleB=1.0*/);
        }
      }
      __builtin_amdgcn_s_setprio(0);

      // theta-filter; packed 4B append (value bf16 hi | chunk-local idx lo)
      const int lbase = (2*i + t) * 64;
      #pragma unroll
      for (int fm = 0; fm < 4; ++fm)
        #pragma unroll
        for (int fn = 0; fn < 4; ++fn) {
          const f32x4 a = acc[fm][fn];
          const float m = fmaxf(fmaxf(a[0], a[1]), fmaxf(a[2], a[3]));
          if (m > THETA) {
            #pragma unroll
            for (int j = 0; j < 4; ++j) {
              if (a[j] > THETA) {
                const int ql = fm*16 + rowb + j;
                const int slot = atomicAdd(&lcnt[wv][ql], 1);
                if (slot < CAPQ) {
                  const unsigned v16 = (unsigned)(unsigned short)f2bf(a[j]);
                  const unsigned loc = (unsigned)(lbase + fn*16 + colb);
                  seg_lds[wv][ql][slot] = (v16 << 16) | loc;
                }
              }
            }
          }
        }
    }

    // drain own ds ops before the next barrier: buffer rotation hazard-free
    asm volatile("s_waitcnt lgkmcnt(0)" ::: "memory");
    __builtin_amdgcn_sched_barrier(0);
  }
#undef STAGE

  // ---- flush wave-private survivor lists to global (lane == wave-local q) ----
  {
    const int cnt = lcnt[wv][lane];
    const int qg = mt*256 + wv*64 + lane;
    cnt_g[qg*NCH + cid] = (unsigned)cnt;
    const int nc = min(cnt, CAPQ);
    unsigned* dst = seg_g + (size_t)(qg*NCH + cid)*CAPQ;
    for (int j = 0; j < nc; ++j) dst[j] = seg_lds[wv][lane][j];
  }
}

// ---------------------------------------------------------------------------
// Kernel 2: per-query gather of survivors -> exact top-16 -> vote.
// Unpacks 4B entries (value = bf16 hi bits; idx = chunk row0 + local).
// Self-check: overflow or <16 survivors -> set flag (triggers fallback).
// ---------------------------------------------------------------------------
__global__ __launch_bounds__(64) void gather_vote_kernel(
    const float* __restrict__ pdb,
    const unsigned* __restrict__ seg_g, const unsigned* __restrict__ cnt_g,
    int* __restrict__ out_label, float* __restrict__ out_s, int* __restrict__ flag)
{
  __shared__ float    cv[NCH*CAPQ];   // 1792
  __shared__ unsigned ci[NCH*CAPQ];
  const int q    = (int)blockIdx.x;
  const int lane = (int)threadIdx.x;

  bool over = false;
  int tot = 0;
  #pragma unroll
  for (int h = 0; h < NCH/64; ++h) {
    const int c = h*64 + lane;
    const int cnt = (int)cnt_g[q*NCH + c];
    over |= (cnt > CAPQ);
    const int nc = min(cnt, CAPQ);
    tot += nc;
    const int r0c = chunk_row0(c);
    const unsigned* src = seg_g + (size_t)(q*NCH + c)*CAPQ;
    for (int j = 0; j < CAPQ; ++j) {
      float v = NEGF; unsigned idx = 0u;
      if (j < nc) {
        const unsigned e = src[j];
        v = __uint_as_float(e & 0xFFFF0000u);   // bf16 value in high bits
        idx = (unsigned)(r0c + (int)(e & 0xFFFFu));
      }
      cv[c*CAPQ + j] = v;
      ci[c*CAPQ + j] = idx;
    }
  }
  #pragma unroll
  for (int off = 32; off >= 1; off >>= 1) tot += __shfl_xor(tot, off);
  __syncthreads();

  float topv[TK]; int topid[TK];
  #pragma unroll
  for (int r = 0; r < TK; ++r) {
    float bv = NEGF; int bp = -1;
    #pragma unroll 4
    for (int j = 0; j < (NCH*CAPQ)/64; ++j) {
      const int p = j*64 + lane;
      const float v = cv[p];
      if (v > bv) { bv = v; bp = p; }
    }
    #pragma unroll
    for (int off = 32; off >= 1; off >>= 1) {
      const float ov = __shfl_xor(bv, off);
      const int   op = __shfl_xor(bp, off);
      if (ov > bv || (ov == bv && ((unsigned)op < (unsigned)bp))) { bv = ov; bp = op; }
    }
    topv[r] = bv;
    int id = -2;
    if (bp >= 0 && bv > NEGF) id = (int)pdb[(size_t)ci[bp]*PDBW + CDIM];
    topid[r] = id;
    if (lane == 0 && bp >= 0) cv[bp] = NEGF;
    __syncthreads();
  }

  if (lane == 0) {
    bool mk[TK];
    int nvalid = 0;
    #pragma unroll
    for (int i = 0; i < TK; ++i) {
      mk[i] = (topv[i] >= MIN_SIM_C) && (topid[i] >= 0);
      nvalid += mk[i] ? 1 : 0;
    }
    int maj = 0, majid = 0x7fffffff;
    for (int i = 0; i < TK; ++i) {
      if (!mk[i]) continue;
      int c = 0;
      for (int j = 0; j < TK; ++j) c += (mk[j] && topid[j] == topid[i]) ? 1 : 0;
      if (c > maj || (c == maj && topid[i] < majid)) { maj = c; majid = topid[i]; }
    }
    const float ratio = (float)maj / fmaxf((float)nvalid, 1.0f);
    const bool valid = (maj > 0) && (ratio >= MIN_VOTES_C);
    const int label = valid ? majid : -1;
    float s = 0.f;
    #pragma unroll
    for (int i = 0; i < TK; ++i)
      if (mk[i] && topid[i] == label) s = fmaxf(s, topv[i]);
    out_label[q] = label;
    out_s[q]     = s;
  }
  const bool bad = (__ballot(over) != 0ull) || (tot < TK);
  if (lane == 0 && bad) atomicOr(flag, 1);
}

// ---------------------------------------------------------------------------
// Fallback stage 1 (round-1, proven): gated on flag
// ---------------------------------------------------------------------------
__global__ __launch_bounds__(256, 2) void sims_topk1_kernel(
    const float* __restrict__ qd, const float* __restrict__ pdb,
    float* __restrict__ cand_val, unsigned int* __restrict__ cand_idx,
    const int* __restrict__ gate)
{
  if (gate && *gate == 0) return;
  __shared__ __align__(16) short db_lds[128 * 264];
  float* sims = (float*)db_lds;

  const int tid  = (int)threadIdx.x;
  const int lane = tid & 63;
  const int wv   = tid >> 6;
  const int cid   = (int)blockIdx.x;
  const int mtile = (int)blockIdx.y;

  bf16x8 aq[2][8];
  {
    const int l15 = lane & 15;
    const int kb  = (lane >> 4) << 3;
    #pragma unroll
    for (int fm = 0; fm < 2; ++fm) {
      const int row = mtile*128 + wv*32 + fm*16 + l15;
      #pragma unroll
      for (int kk = 0; kk < 8; ++kk) {
        const float* p = qd + (size_t)row*CDIM + kk*32 + kb;
        float4 x0 = *(const float4*)p;
        float4 x1 = *(const float4*)(p + 4);
        bf16x8 a;
        a[0]=f2bf(x0.x); a[1]=f2bf(x0.y); a[2]=f2bf(x0.z); a[3]=f2bf(x0.w);
        a[4]=f2bf(x1.x); a[5]=f2bf(x1.y); a[6]=f2bf(x1.z); a[7]=f2bf(x1.w);
        aq[fm][kk] = a;
      }
    }
  }

  float    tv[TK];
  unsigned ti[TK];
  #pragma unroll
  for (int i = 0; i < TK; ++i) { tv[i] = NEGF; ti[i] = 0u; }
  float minv = NEGF; int minp = 0;

  const int g0chunk = cid * 4096;
  const int q_l  = tid & 127;
  const int half = tid >> 7;

  for (int s = 0; s < 32; ++s) {
    const int g0 = g0chunk + s*128;
    {
      const int rb = tid >> 6;
      const int c4 = (tid & 63) << 2;
      for (int i = 0; i < 32; ++i) {
        const int rl = i*4 + rb;
        const int g  = g0 + rl;
        float v0, v1, v2, v3;
        if (g < NDB) {
          const float* p = pdb + (size_t)g*PDBW + c4;
          v0 = p[0]; v1 = p[1]; v2 = p[2]; v3 = p[3];
        } else { v0 = v1 = v2 = v3 = 0.f; }
        short* d = &db_lds[rl*264 + c4];
        d[0]=f2bf(v0); d[1]=f2bf(v1); d[2]=f2bf(v2); d[3]=f2bf(v3);
      }
    }
    __syncthreads();

    f32x4 acc[2][8];
    #pragma unroll
    for (int fm = 0; fm < 2; ++fm)
      #pragma unroll
      for (int fn = 0; fn < 8; ++fn)
        acc[fm][fn] = (f32x4){0.f, 0.f, 0.f, 0.f};
    {
      const int l15 = lane & 15;
      const int kb  = (lane >> 4) << 3;
      #pragma unroll
      for (int kk = 0; kk < 8; ++kk) {
        bf16x8 b[8];
        #pragma unroll
        for (int fn = 0; fn < 8; ++fn)
          b[fn] = *(const bf16x8*)&db_lds[(fn*16 + l15)*264 + kk*32 + kb];
        #pragma unroll
        for (int fn = 0; fn < 8; ++fn) {
          acc[0][fn] = __builtin_amdgcn_mfma_f32_16x16x32_bf16(aq[0][kk], b[fn], acc[0][fn], 0, 0, 0);
          acc[1][fn] = __builtin_amdgcn_mfma_f32_16x16x32_bf16(aq[1][kk], b[fn], acc[1][fn], 0, 0, 0);
        }
      }
    }
    __syncthreads();

    {
      const int colb = lane & 15;
      const int rowb = (lane >> 4) << 2;
      #pragma unroll
      for (int fm = 0; fm < 2; ++fm)
        #pragma unroll
        for (int fn = 0; fn < 8; ++fn)
          #pragma unroll
          for (int j = 0; j < 4; ++j)
            sims[(wv*32 + fm*16 + rowb + j)*129 + fn*16 + colb] = acc[fm][fn][j];
    }
    __syncthreads();

    {
      const int cb = half * 64;
      #pragma unroll 4
      for (int c = 0; c < 64; ++c) {
        const int colc = cb + c;
        const float v = sims[q_l*129 + colc];
        const int g = g0 + colc;
        if (v > minv && g < NDB) {
          #pragma unroll
          for (int i = 0; i < TK; ++i) if (i == minp) { tv[i] = v; ti[i] = (unsigned)g; }
          minv = tv[0]; minp = 0;
          #pragma unroll
          for (int i = 1; i < TK; ++i) if (tv[i] < minv) { minv = tv[i]; minp = i; }
        }
      }
    }
    __syncthreads();
  }

  {
    const int qg = mtile*128 + q_l;
    float*    pv = cand_val + ((size_t)qg*NCHUNK1 + cid)*32 + half*TK;
    unsigned* pi = cand_idx + ((size_t)qg*NCHUNK1 + cid)*32 + half*TK;
    #pragma unroll
    for (int i = 0; i < TK; ++i) { pv[i] = tv[i]; pi[i] = ti[i]; }
  }
}

// ---------------------------------------------------------------------------
// Fallback stage 2 (round-1, proven): gated on flag
// ---------------------------------------------------------------------------
template<int CPQ>
__global__ __launch_bounds__(64) void merge_vote_kernel(
    const float* __restrict__ pdb,
    const float* __restrict__ cand_val, const unsigned* __restrict__ cand_idx,
    int* __restrict__ out_label, float* __restrict__ out_s,
    const int* __restrict__ gate)
{
  if (gate && *gate == 0) return;
  __shared__ float    cv[CPQ];
  __shared__ unsigned ci[CPQ];
  const int q    = (int)blockIdx.x;
  const int lane = (int)threadIdx.x;

  for (int j = lane; j < CPQ; j += 64) {
    cv[j] = cand_val[(size_t)q*CPQ + j];
    ci[j] = cand_idx[(size_t)q*CPQ + j];
  }
  __syncthreads();

  float topv[TK]; int topid[TK];
  #pragma unroll
  for (int r = 0; r < TK; ++r) {
    float bv = NEGF; int bp = -1;
    for (int j = lane; j < CPQ; j += 64) {
      const float v = cv[j];
      if (v > bv) { bv = v; bp = j; }
    }
    #pragma unroll
    for (int off = 32; off >= 1; off >>= 1) {
      const float ov = __shfl_xor(bv, off);
      const int   op = __shfl_xor(bp, off);
      if (ov > bv || (ov == bv && ((unsigned)op < (unsigned)bp))) { bv = ov; bp = op; }
    }
    topv[r] = bv;
    int id = -2;
    if (bp >= 0 && bv > NEGF) id = (int)pdb[(size_t)ci[bp]*PDBW + CDIM];
    topid[r] = id;
    if (lane == 0 && bp >= 0) cv[bp] = NEGF;
    __syncthreads();
  }

  if (lane == 0) {
    bool mk[TK];
    int nvalid = 0;
    #pragma unroll
    for (int i = 0; i < TK; ++i) {
      mk[i] = (topv[i] >= MIN_SIM_C) && (topid[i] >= 0);
      nvalid += mk[i] ? 1 : 0;
    }
    int maj = 0, majid = 0x7fffffff;
    for (int i = 0; i < TK; ++i) {
      if (!mk[i]) continue;
      int c = 0;
      for (int j = 0; j < TK; ++j) c += (mk[j] && topid[j] == topid[i]) ? 1 : 0;
      if (c > maj || (c == maj && topid[i] < majid)) { maj = c; majid = topid[i]; }
    }
    const float ratio = (float)maj / fmaxf((float)nvalid, 1.0f);
    const bool valid = (maj > 0) && (ratio >= MIN_VOTES_C);
    const int label = valid ? majid : -1;
    float s = 0.f;
    #pragma unroll
    for (int i = 0; i < TK; ++i)
      if (mk[i] && topid[i] == label) s = fmaxf(s, topv[i]);
    out_label[q] = label;
    out_s[q]     = s;
  }
}

// ---------------------------------------------------------------------------
// Stage 3: overlap removal + final outputs
// ---------------------------------------------------------------------------
__device__ __forceinline__ bool finitef(float v) {
  return ((__float_as_uint(v) >> 23) & 0xffu) != 0xffu;
}

__global__ __launch_bounds__(64) void finalize_kernel(
    const float* __restrict__ boxes, const int* __restrict__ labels,
    const float* __restrict__ svals, float* __restrict__ out)
{
  const int x    = (int)blockIdx.x;
  const int lane = (int)threadIdx.x;
  const int lx = labels[x];
  const float bx1 = boxes[x*4+0], by1 = boxes[x*4+1];
  const float bx2 = boxes[x*4+2], by2 = boxes[x*4+3];
  const float ax = (bx2 - bx1) * (by2 - by1);

  bool flag = false;
  if (lx >= 0) {
    for (int y = lane; y < QN; y += 64) {
      if (y == x) continue;
      if (labels[y] != lx) continue;
      const float c1 = boxes[y*4+0], c2 = boxes[y*4+1];
      const float c3 = boxes[y*4+2], c4 = boxes[y*4+3];
      const float ay = (c3 - c1) * (c4 - c2);
      const float xi1 = fmaxf(bx1, c1), yi1 = fmaxf(by1, c2);
      const float xi2 = fminf(bx2, c3), yi2 = fminf(by2, c4);
      const float inter = fmaxf(xi2 - xi1, 0.f) * fmaxf(yi2 - yi1, 0.f);
      const float asmall = fminf(ax, ay);
      const float ov = (asmall > 0.f) ? inter / fmaxf(asmall, 1e-12f) : 0.f;
      if (ov >= 0.5f && ay <= ax) flag = true;
    }
  }
  const bool removed = (__ballot(flag) != 0ull);
  const int label = removed ? -1 : lx;
  const float s = svals[x];
  const bool fin = finitef(s) && finitef(bx1) && finitef(by1) && finitef(bx2) && finitef(by2);
  const bool valid = (label >= 0) && fin;

  if (lane == 0) {
    out[4096 + x] = valid ? s : 0.f;
    out[5120 + x] = (float)(valid ? label : -1);
  }
  if (lane < 4) out[x*4 + lane] = boxes[x*4 + lane];
}

// ---------------------------------------------------------------------------
extern "C" void kernel_launch(void* const* d_in, const int* in_sizes, int n_in,
                              void* d_out, int out_size, void* d_ws, size_t ws_size,
                              hipStream_t stream)
{
  const float* boxes = (const float*)d_in[0];
  const float* qd    = (const float*)d_in[1];
  const float* pdb   = (const float*)d_in[2];
  float* out = (float*)d_out;
  char* ws = (char*)d_ws;

  const size_t db_bytes  = (size_t)NDB_PAD * 256;             //  51,216,384 (fp8)
  const size_t seg_bytes = (size_t)QN * NCH * CAPQ * 4;       //   7,340,032
  const size_t cnt_bytes = (size_t)QN * NCH * 4;              //     524,288
  const size_t c1_bytes  = (size_t)QN * CPQ1 * 8;             //  12,845,056 (fallback, aliases seg+cnt)
  const size_t A_bytes   = (seg_bytes + cnt_bytes > c1_bytes) ? seg_bytes + cnt_bytes : c1_bytes;
  const size_t need = db_bytes + A_bytes + (size_t)QN*8 + 64;

  if (ws_size >= need) {
    unsigned char* dbb = (unsigned char*)ws;
    char* A = ws + db_bytes;
    unsigned* seg_g = (unsigned*)A;
    unsigned* cnt_g = (unsigned*)(A + seg_bytes);
    float*    cand_val = (float*)A;
    unsigned* cand_idx = (unsigned*)(A + (size_t)QN*CPQ1*4);
    int*      labels   = (int*)(ws + db_bytes + A_bytes);
    float*    svals    = (float*)(ws + db_bytes + A_bytes + (size_t)QN*4);
    int*      flag     = (int*)(ws + db_bytes + A_bytes + (size_t)QN*8);

    hipLaunchKernelGGL(convert_db_kernel, dim3(2048), dim3(256), 0, stream, pdb, dbb, flag);
    hipLaunchKernelGGL(sims_filter_kernel, dim3(NCH, 4), dim3(256), 0, stream,
                       qd, dbb, seg_g, cnt_g);
    hipLaunchKernelGGL(gather_vote_kernel, dim3(QN), dim3(64), 0, stream,
                       pdb, seg_g, cnt_g, labels, svals, flag);
    hipLaunchKernelGGL(sims_topk1_kernel, dim3(NCHUNK1, 8), dim3(256), 0, stream,
                       qd, pdb, cand_val, cand_idx, flag);
    hipLaunchKernelGGL((merge_vote_kernel<CPQ1>), dim3(QN), dim3(64), 0, stream,
                       pdb, cand_val, cand_idx, labels, svals, flag);
    hipLaunchKernelGGL(finalize_kernel, dim3(QN), dim3(64), 0, stream,
                       boxes, labels, svals, out);
  } else {
    const size_t n1 = (size_t)QN * CPQ1;
    float*    cand_val = (float*)ws;
    unsigned* cand_idx = (unsigned*)(ws + n1*4);
    int*      labels   = (int*)(ws + n1*8);
    float*    svals    = (float*)(ws + n1*8 + (size_t)QN*4);

    hipLaunchKernelGGL(sims_topk1_kernel, dim3(NCHUNK1, 8), dim3(256), 0, stream,
                       qd, pdb, cand_val, cand_idx, (const int*)nullptr);
    hipLaunchKernelGGL((merge_vote_kernel<CPQ1>), dim3(QN), dim3(64), 0, stream,
                       pdb, cand_val, cand_idx, labels, svals, (const int*)nullptr);
    hipLaunchKernelGGL(finalize_kernel, dim3(QN), dim3(64), 0, stream,
                       boxes, labels, svals, out);
  }
}

// Round 18
// 166.165 us; speedup vs baseline: 9.4408x; 1.0001x over previous
//
#include <hip/hip_runtime.h>
#include <hip/hip_bf16.h>

// ---------------- problem constants ----------------
#define QN 1024
#define NDB 200000
#define NDB_PAD 200064        // 3126 tiles of 64 rows
#define PDBW 257
#define CDIM 256
#define TK 16
#define NEGF (-1e30f)
#define MIN_SIM_C 0.05f
#define MIN_VOTES_C 0.3f

// fast path: 128 chunks x 4 mtiles (256 thr, 4 waves x 64 q); fp8 db in ws
// chunks 0..26 have 26 tiles, 27..127 have 24 (27*26 + 101*24 = 3126)
#define NCH 128
#define THETA 0.19f           // P(sim>THETA)=1.18e-3; true 16th-best ~0.236 (fp8 err ~3e-3 -> ~15 sigma)
#define CAPQ 14               // per-(query,chunk) cap (lambda<=1.96; R17-proven empirically)
// fallback (round-1, proven) path
#define NCHUNK1 49
#define CPQ1 (NCHUNK1*32)

typedef __attribute__((ext_vector_type(8))) short bf16x8;
typedef __attribute__((ext_vector_type(4))) float f32x4;
typedef __attribute__((ext_vector_type(8))) int   i32x8;
typedef __attribute__((ext_vector_type(4))) int   i32x4;

__device__ __forceinline__ short f2bf(float f) {
  union { float f; unsigned u; } x; x.f = f;
  unsigned u = x.u;
  return (short)((u + 0x7fffu + ((u >> 16) & 1u)) >> 16);  // RNE
}

// pack 4 floats -> 4 fp8 e4m3 bytes (same converter feeds A and B, and both
// sides use plain-consecutive k order, so the dot product is exact-consistent)
__device__ __forceinline__ unsigned pk_fp8x4(float a, float b, float c, float d) {
  unsigned w = (unsigned)__builtin_amdgcn_cvt_pk_fp8_f32(a, b, 0, false);
  w = (unsigned)__builtin_amdgcn_cvt_pk_fp8_f32(c, d, (int)w, true);
  return w;
}

// chunk geometry: 3126 tiles over 128 chunks (0..26 -> 26 tiles, 27..127 -> 24)
__device__ __forceinline__ int chunk_nsub(int c) { return 24 + (c < 27 ? 2 : 0); }
__device__ __forceinline__ int chunk_row0(int c) { return (24*c + (c < 27 ? 2*c : 54)) << 6; }

// ---------------------------------------------------------------------------
// Kernel 0: pdb fp32 -> fp8 e4m3 in MFMA-OPERAND-MAJOR layout. Per 64-row
// tile (16384 B): record offset = ((kk*4 + fn)*64 + egrp*16 + l15)*32 + b
// holds k-bytes [kk*128 + egrp*32 + b] of db row (fn*16 + l15). A wave's
// B-fragment read is then base + (kk*4+fn)*2048 + lane*32: two coalesced
// dwordx4 loads straight into the mfma operand -- no LDS staging needed.
// Zero-pads rows [NDB, NDB_PAD). Also zeroes the fallback flag.
// ---------------------------------------------------------------------------
__global__ __launch_bounds__(256) void convert_db_kernel(
    const float* __restrict__ pdb, unsigned char* __restrict__ dbb,
    int* __restrict__ flag)
{
  if (blockIdx.x == 0 && threadIdx.x == 0) *flag = 0;
  const int wv = (int)threadIdx.x >> 6, lane = (int)threadIdx.x & 63;
  for (int r = (int)blockIdx.x*4 + wv; r < NDB_PAD; r += (int)gridDim.x*4) {
    unsigned pack = 0u;
    if (r < NDB) {
      const float* p = pdb + (size_t)r*PDBW + lane*4;
      pack = pk_fp8x4(p[0], p[1], p[2], p[3]);
    }
    const int tile = r >> 6, fn = (r >> 4) & 3, l15 = r & 15;
    const int kk   = lane >> 5;             // elem c = lane*4: kk = c>>7
    const int egrp = (lane & 31) >> 3;      // (c&127)>>5
    const int b32  = (lane & 7) << 2;       // c&31
    unsigned char* dst = dbb + (size_t)tile*16384
                       + ((((kk*4 + fn)*64) + egrp*16 + l15) << 5) + b32;
    *(unsigned*)dst = pack;
  }
}

// ---------------------------------------------------------------------------
// Kernel 1: MX-fp8 (K=128, unit scale) MFMA sims + register theta-filter +
// wave-private LDS survivor lists (packed 4B: bf16val<<16 | chunk-local idx).
// grid (128 chunks, 4 mtiles) = 512 blocks, 256 thr (4 waves x 64 q).
// ZERO-SYNC STRUCTURE: B-fragments are loaded DIRECTLY from the operand-major
// global layout into registers (2 coalesced dwordx4 per fragment) -- no db
// LDS, no barriers, no DMA, no vmcnt. Rationale: R7-R17 all share a
// barrier+DMA skeleton whose per-tile cost (~4.1us) is ~3x the compute
// floor with MfmaUtil~17%/VALU~15% (latency-bound, unexplained); removing
// the skeleton lets the compiler pipeline loads across tiles freely.
// The 16KB tile is wave-shared (L1 dedup); chunk-sharing mtile blocks are
// ids x, x+128, x+256, x+384 == x mod 8 -> same XCD -> L2 hits.
// (256,3): 170-reg budget >> live ~121 (aq 64 + fn-split acc 32 + temps)
// -> no spill; 12 waves/CU (1.5x R17). LDS = 15.4KB survivors only.
// ---------------------------------------------------------------------------
__global__ __launch_bounds__(256, 3) void sims_filter_kernel(
    const float* __restrict__ qd, const unsigned char* __restrict__ dbb,
    unsigned int* __restrict__ seg_g, unsigned int* __restrict__ cnt_g)
{
  __shared__ unsigned seg_lds[4][64][CAPQ];            // 14336 B (wave-private)
  __shared__ int lcnt[4][64];                          // 1024 B (wave-private)

  const int tid  = (int)threadIdx.x;
  const int lane = tid & 63;
  const int wv   = tid >> 6;          // 0..3
  const int cid  = (int)blockIdx.x;   // 0..127
  const int mt   = (int)blockIdx.y;   // 0..3
  const int nsub = chunk_nsub(cid);
  const int row0 = chunk_row0(cid);

  lcnt[wv][lane] = 0;   // wave-private, no barrier needed

  const int l15  = lane & 15;
  const int egrp = lane >> 4;         // k-chunk group 0..3 (32 k each)
  const int rowb = egrp << 2;
  const int colb = l15;

  // ---- Q fragments: fp32 -> fp8 packed i32x8; wave wv owns 64 queries ----
  i32x8 aq[4][2];
  {
    #pragma unroll
    for (int fm = 0; fm < 4; ++fm) {
      const float* qrow = qd + (size_t)(mt*256 + wv*64 + fm*16 + l15)*CDIM;
      #pragma unroll
      for (int kk = 0; kk < 2; ++kk) {
        const float* p = qrow + kk*128 + egrp*32;
        i32x8 a;
        #pragma unroll
        for (int d = 0; d < 8; ++d) {
          float4 x = *(const float4*)(p + d*4);
          a[d] = (int)pk_fp8x4(x.x, x.y, x.z, x.w);
        }
        aq[fm][kk] = a;
      }
    }
  }

  const char* tbase = (const char*)dbb + (size_t)(row0 >> 6) * 16384;

  for (int s = 0; s < nsub; ++s) {
    const char* tb = tbase + (size_t)s * 16384;

    // ---- fn-split: two halves, each MFMA (acc[4][2]) then filter ----
    #pragma unroll
    for (int h = 0; h < 2; ++h) {
      f32x4 acc[4][2];
      #pragma unroll
      for (int fm = 0; fm < 4; ++fm)
        #pragma unroll
        for (int fnl = 0; fnl < 2; ++fnl)
          acc[fm][fnl] = (f32x4){0.f, 0.f, 0.f, 0.f};

      __builtin_amdgcn_s_setprio(1);
      #pragma unroll
      for (int kk = 0; kk < 2; ++kk) {
        #pragma unroll
        for (int fnl = 0; fnl < 2; ++fnl) {
          const int fn = h*2 + fnl;
          const char* p = tb + (((kk*4 + fn)*64 + lane) << 5);
          i32x4 lo = *(const i32x4*)p;
          i32x4 hi = *(const i32x4*)(p + 16);
          i32x8 b = __builtin_shufflevector(lo, hi, 0, 1, 2, 3, 4, 5, 6, 7);
          #pragma unroll
          for (int fm = 0; fm < 4; ++fm)
            acc[fm][fnl] = __builtin_amdgcn_mfma_scale_f32_16x16x128_f8f6f4(
                aq[fm][kk], b, acc[fm][fnl],
                0 /*fmtA=fp8*/, 0 /*fmtB=fp8*/,
                0, 0x7F7F7F7Fu /*scaleA=1.0*/, 0, 0x7F7F7F7Fu /*scaleB=1.0*/);
        }
      }
      __builtin_amdgcn_s_setprio(0);

      // theta-filter; packed 4B append (value bf16 hi | chunk-local idx lo)
      #pragma unroll
      for (int fm = 0; fm < 4; ++fm)
        #pragma unroll
        for (int fnl = 0; fnl < 2; ++fnl) {
          const f32x4 a = acc[fm][fnl];
          const float m = fmaxf(fmaxf(a[0], a[1]), fmaxf(a[2], a[3]));
          if (m > THETA) {
            #pragma unroll
            for (int j = 0; j < 4; ++j) {
              if (a[j] > THETA) {
                const int ql = fm*16 + rowb + j;
                const int slot = atomicAdd(&lcnt[wv][ql], 1);
                if (slot < CAPQ) {
                  const unsigned v16 = (unsigned)(unsigned short)f2bf(a[j]);
                  const unsigned loc = (unsigned)(s*64 + (h*2 + fnl)*16 + colb);
                  seg_lds[wv][ql][slot] = (v16 << 16) | loc;
                }
              }
            }
          }
        }
    }
  }

  // ---- flush wave-private survivor lists to global (lane == wave-local q) ----
  {
    const int cnt = lcnt[wv][lane];
    const int qg = mt*256 + wv*64 + lane;
    cnt_g[qg*NCH + cid] = (unsigned)cnt;
    const int nc = min(cnt, CAPQ);
    unsigned* dst = seg_g + (size_t)(qg*NCH + cid)*CAPQ;
    for (int j = 0; j < nc; ++j) dst[j] = seg_lds[wv][lane][j];
  }
}

// ---------------------------------------------------------------------------
// Kernel 2: per-query gather of survivors -> exact top-16 -> vote.
// Unpacks 4B entries (value = bf16 hi bits; idx = chunk row0 + local).
// Self-check: overflow or <16 survivors -> set flag (triggers fallback).
// ---------------------------------------------------------------------------
__global__ __launch_bounds__(64) void gather_vote_kernel(
    const float* __restrict__ pdb,
    const unsigned* __restrict__ seg_g, const unsigned* __restrict__ cnt_g,
    int* __restrict__ out_label, float* __restrict__ out_s, int* __restrict__ flag)
{
  __shared__ float    cv[NCH*CAPQ];   // 1792
  __shared__ unsigned ci[NCH*CAPQ];
  const int q    = (int)blockIdx.x;
  const int lane = (int)threadIdx.x;

  bool over = false;
  int tot = 0;
  #pragma unroll
  for (int h = 0; h < NCH/64; ++h) {
    const int c = h*64 + lane;
    const int cnt = (int)cnt_g[q*NCH + c];
    over |= (cnt > CAPQ);
    const int nc = min(cnt, CAPQ);
    tot += nc;
    const int r0c = chunk_row0(c);
    const unsigned* src = seg_g + (size_t)(q*NCH + c)*CAPQ;
    for (int j = 0; j < CAPQ; ++j) {
      float v = NEGF; unsigned idx = 0u;
      if (j < nc) {
        const unsigned e = src[j];
        v = __uint_as_float(e & 0xFFFF0000u);   // bf16 value in high bits
        idx = (unsigned)(r0c + (int)(e & 0xFFFFu));
      }
      cv[c*CAPQ + j] = v;
      ci[c*CAPQ + j] = idx;
    }
  }
  #pragma unroll
  for (int off = 32; off >= 1; off >>= 1) tot += __shfl_xor(tot, off);
  __syncthreads();

  float topv[TK]; int topid[TK];
  #pragma unroll
  for (int r = 0; r < TK; ++r) {
    float bv = NEGF; int bp = -1;
    #pragma unroll 4
    for (int j = 0; j < (NCH*CAPQ)/64; ++j) {
      const int p = j*64 + lane;
      const float v = cv[p];
      if (v > bv) { bv = v; bp = p; }
    }
    #pragma unroll
    for (int off = 32; off >= 1; off >>= 1) {
      const float ov = __shfl_xor(bv, off);
      const int   op = __shfl_xor(bp, off);
      if (ov > bv || (ov == bv && ((unsigned)op < (unsigned)bp))) { bv = ov; bp = op; }
    }
    topv[r] = bv;
    int id = -2;
    if (bp >= 0 && bv > NEGF) id = (int)pdb[(size_t)ci[bp]*PDBW + CDIM];
    topid[r] = id;
    if (lane == 0 && bp >= 0) cv[bp] = NEGF;
    __syncthreads();
  }

  if (lane == 0) {
    bool mk[TK];
    int nvalid = 0;
    #pragma unroll
    for (int i = 0; i < TK; ++i) {
      mk[i] = (topv[i] >= MIN_SIM_C) && (topid[i] >= 0);
      nvalid += mk[i] ? 1 : 0;
    }
    int maj = 0, majid = 0x7fffffff;
    for (int i = 0; i < TK; ++i) {
      if (!mk[i]) continue;
      int c = 0;
      for (int j = 0; j < TK; ++j) c += (mk[j] && topid[j] == topid[i]) ? 1 : 0;
      if (c > maj || (c == maj && topid[i] < majid)) { maj = c; majid = topid[i]; }
    }
    const float ratio = (float)maj / fmaxf((float)nvalid, 1.0f);
    const bool valid = (maj > 0) && (ratio >= MIN_VOTES_C);
    const int label = valid ? majid : -1;
    float s = 0.f;
    #pragma unroll
    for (int i = 0; i < TK; ++i)
      if (mk[i] && topid[i] == label) s = fmaxf(s, topv[i]);
    out_label[q] = label;
    out_s[q]     = s;
  }
  const bool bad = (__ballot(over) != 0ull) || (tot < TK);
  if (lane == 0 && bad) atomicOr(flag, 1);
}

// ---------------------------------------------------------------------------
// Fallback stage 1 (round-1, proven): gated on flag
// ---------------------------------------------------------------------------
__global__ __launch_bounds__(256, 2) void sims_topk1_kernel(
    const float* __restrict__ qd, const float* __restrict__ pdb,
    float* __restrict__ cand_val, unsigned int* __restrict__ cand_idx,
    const int* __restrict__ gate)
{
  if (gate && *gate == 0) return;
  __shared__ __align__(16) short db_lds[128 * 264];
  float* sims = (float*)db_lds;

  const int tid  = (int)threadIdx.x;
  const int lane = tid & 63;
  const int wv   = tid >> 6;
  const int cid   = (int)blockIdx.x;
  const int mtile = (int)blockIdx.y;

  bf16x8 aq[2][8];
  {
    const int l15 = lane & 15;
    const int kb  = (lane >> 4) << 3;
    #pragma unroll
    for (int fm = 0; fm < 2; ++fm) {
      const int row = mtile*128 + wv*32 + fm*16 + l15;
      #pragma unroll
      for (int kk = 0; kk < 8; ++kk) {
        const float* p = qd + (size_t)row*CDIM + kk*32 + kb;
        float4 x0 = *(const float4*)p;
        float4 x1 = *(const float4*)(p + 4);
        bf16x8 a;
        a[0]=f2bf(x0.x); a[1]=f2bf(x0.y); a[2]=f2bf(x0.z); a[3]=f2bf(x0.w);
        a[4]=f2bf(x1.x); a[5]=f2bf(x1.y); a[6]=f2bf(x1.z); a[7]=f2bf(x1.w);
        aq[fm][kk] = a;
      }
    }
  }

  float    tv[TK];
  unsigned ti[TK];
  #pragma unroll
  for (int i = 0; i < TK; ++i) { tv[i] = NEGF; ti[i] = 0u; }
  float minv = NEGF; int minp = 0;

  const int g0chunk = cid * 4096;
  const int q_l  = tid & 127;
  const int half = tid >> 7;

  for (int s = 0; s < 32; ++s) {
    const int g0 = g0chunk + s*128;
    {
      const int rb = tid >> 6;
      const int c4 = (tid & 63) << 2;
      for (int i = 0; i < 32; ++i) {
        const int rl = i*4 + rb;
        const int g  = g0 + rl;
        float v0, v1, v2, v3;
        if (g < NDB) {
          const float* p = pdb + (size_t)g*PDBW + c4;
          v0 = p[0]; v1 = p[1]; v2 = p[2]; v3 = p[3];
        } else { v0 = v1 = v2 = v3 = 0.f; }
        short* d = &db_lds[rl*264 + c4];
        d[0]=f2bf(v0); d[1]=f2bf(v1); d[2]=f2bf(v2); d[3]=f2bf(v3);
      }
    }
    __syncthreads();

    f32x4 acc[2][8];
    #pragma unroll
    for (int fm = 0; fm < 2; ++fm)
      #pragma unroll
      for (int fn = 0; fn < 8; ++fn)
        acc[fm][fn] = (f32x4){0.f, 0.f, 0.f, 0.f};
    {
      const int l15 = lane & 15;
      const int kb  = (lane >> 4) << 3;
      #pragma unroll
      for (int kk = 0; kk < 8; ++kk) {
        bf16x8 b[8];
        #pragma unroll
        for (int fn = 0; fn < 8; ++fn)
          b[fn] = *(const bf16x8*)&db_lds[(fn*16 + l15)*264 + kk*32 + kb];
        #pragma unroll
        for (int fn = 0; fn < 8; ++fn) {
          acc[0][fn] = __builtin_amdgcn_mfma_f32_16x16x32_bf16(aq[0][kk], b[fn], acc[0][fn], 0, 0, 0);
          acc[1][fn] = __builtin_amdgcn_mfma_f32_16x16x32_bf16(aq[1][kk], b[fn], acc[1][fn], 0, 0, 0);
        }
      }
    }
    __syncthreads();

    {
      const int colb = lane & 15;
      const int rowb = (lane >> 4) << 2;
      #pragma unroll
      for (int fm = 0; fm < 2; ++fm)
        #pragma unroll
        for (int fn = 0; fn < 8; ++fn)
          #pragma unroll
          for (int j = 0; j < 4; ++j)
            sims[(wv*32 + fm*16 + rowb + j)*129 + fn*16 + colb] = acc[fm][fn][j];
    }
    __syncthreads();

    {
      const int cb = half * 64;
      #pragma unroll 4
      for (int c = 0; c < 64; ++c) {
        const int colc = cb + c;
        const float v = sims[q_l*129 + colc];
        const int g = g0 + colc;
        if (v > minv && g < NDB) {
          #pragma unroll
          for (int i = 0; i < TK; ++i) if (i == minp) { tv[i] = v; ti[i] = (unsigned)g; }
          minv = tv[0]; minp = 0;
          #pragma unroll
          for (int i = 1; i < TK; ++i) if (tv[i] < minv) { minv = tv[i]; minp = i; }
        }
      }
    }
    __syncthreads();
  }

  {
    const int qg = mtile*128 + q_l;
    float*    pv = cand_val + ((size_t)qg*NCHUNK1 + cid)*32 + half*TK;
    unsigned* pi = cand_idx + ((size_t)qg*NCHUNK1 + cid)*32 + half*TK;
    #pragma unroll
    for (int i = 0; i < TK; ++i) { pv[i] = tv[i]; pi[i] = ti[i]; }
  }
}

// ---------------------------------------------------------------------------
// Fallback stage 2 (round-1, proven): gated on flag
// ---------------------------------------------------------------------------
template<int CPQ>
__global__ __launch_bounds__(64) void merge_vote_kernel(
    const float* __restrict__ pdb,
    const float* __restrict__ cand_val, const unsigned* __restrict__ cand_idx,
    int* __restrict__ out_label, float* __restrict__ out_s,
    const int* __restrict__ gate)
{
  if (gate && *gate == 0) return;
  __shared__ float    cv[CPQ];
  __shared__ unsigned ci[CPQ];
  const int q    = (int)blockIdx.x;
  const int lane = (int)threadIdx.x;

  for (int j = lane; j < CPQ; j += 64) {
    cv[j] = cand_val[(size_t)q*CPQ + j];
    ci[j] = cand_idx[(size_t)q*CPQ + j];
  }
  __syncthreads();

  float topv[TK]; int topid[TK];
  #pragma unroll
  for (int r = 0; r < TK; ++r) {
    float bv = NEGF; int bp = -1;
    for (int j = lane; j < CPQ; j += 64) {
      const float v = cv[j];
      if (v > bv) { bv = v; bp = j; }
    }
    #pragma unroll
    for (int off = 32; off >= 1; off >>= 1) {
      const float ov = __shfl_xor(bv, off);
      const int   op = __shfl_xor(bp, off);
      if (ov > bv || (ov == bv && ((unsigned)op < (unsigned)bp))) { bv = ov; bp = op; }
    }
    topv[r] = bv;
    int id = -2;
    if (bp >= 0 && bv > NEGF) id = (int)pdb[(size_t)ci[bp]*PDBW + CDIM];
    topid[r] = id;
    if (lane == 0 && bp >= 0) cv[bp] = NEGF;
    __syncthreads();
  }

  if (lane == 0) {
    bool mk[TK];
    int nvalid = 0;
    #pragma unroll
    for (int i = 0; i < TK; ++i) {
      mk[i] = (topv[i] >= MIN_SIM_C) && (topid[i] >= 0);
      nvalid += mk[i] ? 1 : 0;
    }
    int maj = 0, majid = 0x7fffffff;
    for (int i = 0; i < TK; ++i) {
      if (!mk[i]) continue;
      int c = 0;
      for (int j = 0; j < TK; ++j) c += (mk[j] && topid[j] == topid[i]) ? 1 : 0;
      if (c > maj || (c == maj && topid[i] < majid)) { maj = c; majid = topid[i]; }
    }
    const float ratio = (float)maj / fmaxf((float)nvalid, 1.0f);
    const bool valid = (maj > 0) && (ratio >= MIN_VOTES_C);
    const int label = valid ? majid : -1;
    float s = 0.f;
    #pragma unroll
    for (int i = 0; i < TK; ++i)
      if (mk[i] && topid[i] == label) s = fmaxf(s, topv[i]);
    out_label[q] = label;
    out_s[q]     = s;
  }
}

// ---------------------------------------------------------------------------
// Stage 3: overlap removal + final outputs
// ---------------------------------------------------------------------------
__device__ __forceinline__ bool finitef(float v) {
  return ((__float_as_uint(v) >> 23) & 0xffu) != 0xffu;
}

__global__ __launch_bounds__(64) void finalize_kernel(
    const float* __restrict__ boxes, const int* __restrict__ labels,
    const float* __restrict__ svals, float* __restrict__ out)
{
  const int x    = (int)blockIdx.x;
  const int lane = (int)threadIdx.x;
  const int lx = labels[x];
  const float bx1 = boxes[x*4+0], by1 = boxes[x*4+1];
  const float bx2 = boxes[x*4+2], by2 = boxes[x*4+3];
  const float ax = (bx2 - bx1) * (by2 - by1);

  bool flag = false;
  if (lx >= 0) {
    for (int y = lane; y < QN; y += 64) {
      if (y == x) continue;
      if (labels[y] != lx) continue;
      const float c1 = boxes[y*4+0], c2 = boxes[y*4+1];
      const float c3 = boxes[y*4+2], c4 = boxes[y*4+3];
      const float ay = (c3 - c1) * (c4 - c2);
      const float xi1 = fmaxf(bx1, c1), yi1 = fmaxf(by1, c2);
      const float xi2 = fminf(bx2, c3), yi2 = fminf(by2, c4);
      const float inter = fmaxf(xi2 - xi1, 0.f) * fmaxf(yi2 - yi1, 0.f);
      const float asmall = fminf(ax, ay);
      const float ov = (asmall > 0.f) ? inter / fmaxf(asmall, 1e-12f) : 0.f;
      if (ov >= 0.5f && ay <= ax) flag = true;
    }
  }
  const bool removed = (__ballot(flag) != 0ull);
  const int label = removed ? -1 : lx;
  const float s = svals[x];
  const bool fin = finitef(s) && finitef(bx1) && finitef(by1) && finitef(bx2) && finitef(by2);
  const bool valid = (label >= 0) && fin;

  if (lane == 0) {
    out[4096 + x] = valid ? s : 0.f;
    out[5120 + x] = (float)(valid ? label : -1);
  }
  if (lane < 4) out[x*4 + lane] = boxes[x*4 + lane];
}

// ---------------------------------------------------------------------------
extern "C" void kernel_launch(void* const* d_in, const int* in_sizes, int n_in,
                              void* d_out, int out_size, void* d_ws, size_t ws_size,
                              hipStream_t stream)
{
  const float* boxes = (const float*)d_in[0];
  const float* qd    = (const float*)d_in[1];
  const float* pdb   = (const float*)d_in[2];
  float* out = (float*)d_out;
  char* ws = (char*)d_ws;

  const size_t db_bytes  = (size_t)NDB_PAD * 256;             //  51,216,384 (fp8)
  const size_t seg_bytes = (size_t)QN * NCH * CAPQ * 4;       //   7,340,032
  const size_t cnt_bytes = (size_t)QN * NCH * 4;              //     524,288
  const size_t c1_bytes  = (size_t)QN * CPQ1 * 8;             //  12,845,056 (fallback, aliases seg+cnt)
  const size_t A_bytes   = (seg_bytes + cnt_bytes > c1_bytes) ? seg_bytes + cnt_bytes : c1_bytes;
  const size_t need = db_bytes + A_bytes + (size_t)QN*8 + 64;

  if (ws_size >= need) {
    unsigned char* dbb = (unsigned char*)ws;
    char* A = ws + db_bytes;
    unsigned* seg_g = (unsigned*)A;
    unsigned* cnt_g = (unsigned*)(A + seg_bytes);
    float*    cand_val = (float*)A;
    unsigned* cand_idx = (unsigned*)(A + (size_t)QN*CPQ1*4);
    int*      labels   = (int*)(ws + db_bytes + A_bytes);
    float*    svals    = (float*)(ws + db_bytes + A_bytes + (size_t)QN*4);
    int*      flag     = (int*)(ws + db_bytes + A_bytes + (size_t)QN*8);

    hipLaunchKernelGGL(convert_db_kernel, dim3(2048), dim3(256), 0, stream, pdb, dbb, flag);
    hipLaunchKernelGGL(sims_filter_kernel, dim3(NCH, 4), dim3(256), 0, stream,
                       qd, dbb, seg_g, cnt_g);
    hipLaunchKernelGGL(gather_vote_kernel, dim3(QN), dim3(64), 0, stream,
                       pdb, seg_g, cnt_g, labels, svals, flag);
    hipLaunchKernelGGL(sims_topk1_kernel, dim3(NCHUNK1, 8), dim3(256), 0, stream,
                       qd, pdb, cand_val, cand_idx, flag);
    hipLaunchKernelGGL((merge_vote_kernel<CPQ1>), dim3(QN), dim3(64), 0, stream,
                       pdb, cand_val, cand_idx, labels, svals, flag);
    hipLaunchKernelGGL(finalize_kernel, dim3(QN), dim3(64), 0, stream,
                       boxes, labels, svals, out);
  } else {
    const size_t n1 = (size_t)QN * CPQ1;
    float*    cand_val = (float*)ws;
    unsigned* cand_idx = (unsigned*)(ws + n1*4);
    int*      labels   = (int*)(ws + n1*8);
    float*    svals    = (float*)(ws + n1*8 + (size_t)QN*4);

    hipLaunchKernelGGL(sims_topk1_kernel, dim3(NCHUNK1, 8), dim3(256), 0, stream,
                       qd, pdb, cand_val, cand_idx, (const int*)nullptr);
    hipLaunchKernelGGL((merge_vote_kernel<CPQ1>), dim3(QN), dim3(64), 0, stream,
                       pdb, cand_val, cand_idx, labels, svals, (const int*)nullptr);
    hipLaunchKernelGGL(finalize_kernel, dim3(QN), dim3(64), 0, stream,
                       boxes, labels, svals, out);
  }
}